// Round 3
// baseline (3873.178 us; speedup 1.0000x reference)
//
#include <hip/hip_runtime.h>
#include <hip/hip_cooperative_groups.h>

namespace cg = cooperative_groups;

#define LSEQ 400
#define BATCH 256
#define EMBD 256
#define HIDD 512
#define KDIM 768   // EMB + HID
#define NJ 41      // K+1

typedef __attribute__((ext_vector_type(8))) short short8x;
typedef __attribute__((ext_vector_type(4))) float f32x4;

__device__ __forceinline__ float bf2f(unsigned short u) {
    union { unsigned int i; float f; } v; v.i = ((unsigned int)u) << 16; return v.f;
}
__device__ __forceinline__ unsigned short f2bf(float f) {
    union { float f; unsigned int i; } v; v.f = f;
    unsigned int x = v.i;
    return (unsigned short)((x + 0x7fffu + ((x >> 16) & 1u)) >> 16);
}
__device__ __forceinline__ float sigm(float x) { return 1.0f / (1.0f + __expf(-x)); }

// ---------------------------------------------------------------------------
// Prologue: pack W_ih|W_hh (f32) into bf16 MFMA-fragment order; init state.
// pW layout: [gg(64)][mt(2)][kt(24)][lane(64)] x short8; WG "gg" owns hidden
// units [gg*8, gg*8+8); local row r = mt*16+(lane&15), gate=r>>3, hu=r&7,
// global row = gate*512+gg*8+hu, k = kt*32+(lane>>4)*8+j (same bijection on B).
// ---------------------------------------------------------------------------
__global__ __launch_bounds__(256) void prologue_kernel(
    const float* __restrict__ W_ih, const float* __restrict__ W_hh,
    const int* __restrict__ xs, const float* __restrict__ embW,
    const float* __restrict__ mask,
    unsigned short* __restrict__ pW, unsigned short* __restrict__ xh0,
    int* __restrict__ base_rows)
{
    int wg = blockIdx.x, t = threadIdx.x;
    int gg = wg >> 2, part = wg & 3;
    int lane = t & 63, sub = t >> 6;
    for (int q = 0; q < 3; ++q) {
        int f = sub * 3 + q;                 // 0..11
        int mt = f / 6, kt = part * 6 + (f % 6);
        int r = mt * 16 + (lane & 15);
        int gate = r >> 3, hu = r & 7;
        int grow = gate * 512 + gg * 8 + hu;
        int k0 = kt * 32 + ((lane >> 4) << 3);
        union { short8x v; unsigned short u[8]; } pk;
        #pragma unroll
        for (int j = 0; j < 8; ++j) {
            int k = k0 + j;
            float wv = (k < EMBD) ? W_ih[(size_t)grow * EMBD + k]
                                  : W_hh[(size_t)grow * HIDD + (k - EMBD)];
            pk.u[j] = f2bf(wv);
        }
        ((short8x*)pW)[((size_t)(gg * 2 + mt) * 24 + kt) * 64 + lane] = pk.v;
    }
    // per-batch state init (b = wg): x for step 0 (row 0), h=0, base=0
    int b = wg;
    int tok = xs[b];   // row 0
    float ev = embW[(size_t)tok * EMBD + t] * mask[(size_t)b * EMBD + t];
    xh0[(size_t)b * KDIM + t] = f2bf(ev);
    for (int e = t; e < HIDD; e += 256) xh0[(size_t)b * KDIM + EMBD + e] = 0;
    if (t == 0) base_rows[b] = 0;
}

// ---------------------------------------------------------------------------
// Persistent cooperative kernel: all 105 LSTM steps + 5 boundaries + final.
// 256 WGs (1/CU) = 64 gate-groups x 4 batch-groups. A fragments, c, h, biases
// resident in registers across the whole sequence; grid.sync() per step.
// ---------------------------------------------------------------------------
__global__ __launch_bounds__(256, 1) void persistent_kernel(
    const unsigned short* __restrict__ pW,
    unsigned short* __restrict__ xh,           // 2 double-buffered [256][768]
    int* __restrict__ base_rows,
    const float* __restrict__ b_ih, const float* __restrict__ b_hh,
    const int* __restrict__ xs, const float* __restrict__ embW,
    const float* __restrict__ mask,
    const float* __restrict__ W_jump, const float* __restrict__ b_jump,
    const float* __restrict__ W_base, const float* __restrict__ b_base,
    const float* __restrict__ gumbel,
    float* __restrict__ lp_arr, float* __restrict__ base_arr,
    const float* __restrict__ W_out, const float* __restrict__ b_out,
    const int* __restrict__ tcls,
    float* __restrict__ loss_arr, float* __restrict__ out)
{
    cg::grid_group grid = cg::this_grid();

    __shared__ float gates[32][65];
    __shared__ __align__(16) unsigned short hstage[64][8];
    __shared__ float zsh[42];
    __shared__ int rowsh;

    const int wg = blockIdx.x;
    const int gg = wg >> 2, bg = wg & 3;
    const int tid = threadIdx.x, lane = tid & 63, w = tid >> 6;
    const int mhalf = w >> 1, npair = w & 1;

    // --- A fragments: registers for the whole sequence (24 x short8x) ---
    const short8x* Ab = ((const short8x*)pW) + ((size_t)(gg * 2 + mhalf) * 24) * 64 + lane;
    short8x Areg[24];
    #pragma unroll
    for (int kt = 0; kt < 24; ++kt) Areg[kt] = Ab[kt * 64];

    const int bcol0 = bg * 64 + npair * 32 + (lane & 15);
    const int krow  = (lane >> 4) << 3;

    // --- elementwise thread mapping: hu = tid>>5, two local cols ---
    const int hu  = tid >> 5;
    const int hid = gg * 8 + hu;
    const float bi  = b_ih[hid]        + b_hh[hid];
    const float bf_ = b_ih[512 + hid]  + b_hh[512 + hid];
    const float bgt = b_ih[1024 + hid] + b_hh[1024 + hid];
    const float bo  = b_ih[1536 + hid] + b_hh[1536 + hid];
    const int bl0 = (tid & 31) << 1;
    const int bcol_a = bg * 64 + bl0, bcol_b = bcol_a + 1;

    float c0 = 0.f, c1 = 0.f, h0 = 0.f, h1 = 0.f;   // resident LSTM state
    int br0 = 0, br1 = 0;                           // base rows for my 2 cols

    const size_t XH = (size_t)BATCH * KDIM;
    int p = 0;

    for (int n = 0; n < 5; ++n) {
        for (int i = 0; i <= 20; ++i) {
            const unsigned short* xin  = xh + (size_t)p * XH;
            unsigned short*       xout = xh + (size_t)(p ^ 1) * XH;
            const short8x* B0 = (const short8x*)(xin + (size_t)bcol0 * KDIM + krow);
            const short8x* B1 = (const short8x*)(xin + (size_t)(bcol0 + 16) * KDIM + krow);

            f32x4 acc0a = {0,0,0,0}, acc0b = {0,0,0,0};
            f32x4 acc1a = {0,0,0,0}, acc1b = {0,0,0,0};
            #pragma unroll
            for (int kt = 0; kt < 24; kt += 2) {
                short8x b00 = B0[kt * 4];
                short8x b01 = B0[(kt + 1) * 4];
                short8x b10 = B1[kt * 4];
                short8x b11 = B1[(kt + 1) * 4];
                acc0a = __builtin_amdgcn_mfma_f32_16x16x32_bf16(Areg[kt],     b00, acc0a, 0, 0, 0);
                acc1a = __builtin_amdgcn_mfma_f32_16x16x32_bf16(Areg[kt],     b10, acc1a, 0, 0, 0);
                acc0b = __builtin_amdgcn_mfma_f32_16x16x32_bf16(Areg[kt + 1], b01, acc0b, 0, 0, 0);
                acc1b = __builtin_amdgcn_mfma_f32_16x16x32_bf16(Areg[kt + 1], b11, acc1b, 0, 0, 0);
            }
            f32x4 acc0 = acc0a + acc0b, acc1 = acc1a + acc1b;

            int rbase = mhalf * 16 + ((lane >> 4) << 2);
            int cix   = npair * 32 + (lane & 15);
            #pragma unroll
            for (int v = 0; v < 4; ++v) {     // C/D map: col=lane&15, row=(lane>>4)*4+v
                gates[rbase + v][cix]      = acc0[v];
                gates[rbase + v][cix + 16] = acc1[v];
            }
            __syncthreads();

            // elementwise LSTM on resident state
            {
                bool fp = (br0 + i) >= LSEQ;
                float gi = gates[hu][bl0]      + bi;
                float gf = gates[8 + hu][bl0]  + bf_;
                float gc = gates[16 + hu][bl0] + bgt;
                float go = gates[24 + hu][bl0] + bo;
                float c2 = sigm(gf) * c0 + sigm(gi) * tanhf(gc);
                float h2 = sigm(go) * tanhf(c2);
                if (!fp) { c0 = c2; h0 = h2; }
                hstage[bl0][hu] = f2bf(h0);
            }
            {
                bool fp = (br1 + i) >= LSEQ;
                float gi = gates[hu][bl0 + 1]      + bi;
                float gf = gates[8 + hu][bl0 + 1]  + bf_;
                float gc = gates[16 + hu][bl0 + 1] + bgt;
                float go = gates[24 + hu][bl0 + 1] + bo;
                float c2 = sigm(gf) * c1 + sigm(gi) * tanhf(gc);
                float h2 = sigm(go) * tanhf(c2);
                if (!fp) { c1 = c2; h1 = h2; }
                hstage[bl0 + 1][hu] = f2bf(h1);
            }
            __syncthreads();
            if (tid < 64) {
                int b = bg * 64 + tid;
                short8x hv = *((const short8x*)&hstage[tid][0]);
                *((short8x*)(xout + (size_t)b * KDIM + EMBD + gg * 8)) = hv;
            }
            if (i < 20) {                      // fused gather of next x (b = wg)
                int b = wg;
                int br = base_rows[b];
                int row = br + i + 1; if (row > LSEQ - 1) row = LSEQ - 1;
                int tok = xs[(size_t)row * BATCH + b];
                float ev = embW[(size_t)tok * EMBD + tid] *
                           mask[((size_t)row * BATCH + b) * EMBD + tid];
                xout[(size_t)b * KDIM + tid] = f2bf(ev);
            }
            p ^= 1;
            grid.sync();

            if (i == 20) {
                // ---------------- boundary (one WG per batch elem) ----------
                unsigned short* xcur = xh + (size_t)p * XH;
                int b = wg;
                const unsigned short* hp = xcur + (size_t)b * KDIM + EMBD;
                union { short8x v; unsigned short u[8]; } hv;
                hv.v = *(const short8x*)(hp + lane * 8);
                float hf[8];
                #pragma unroll
                for (int j = 0; j < 8; ++j) hf[j] = bf2f(hv.u[j]);

                for (int r = w; r < 42; r += 4) {
                    const float* wr = (r < NJ) ? (W_jump + (size_t)r * HIDD) : W_base;
                    const float4* wp = (const float4*)(wr + lane * 8);
                    float4 w0 = wp[0], w1 = wp[1];
                    float acc = w0.x*hf[0] + w0.y*hf[1] + w0.z*hf[2] + w0.w*hf[3]
                              + w1.x*hf[4] + w1.y*hf[5] + w1.z*hf[6] + w1.w*hf[7];
                    #pragma unroll
                    for (int off = 32; off > 0; off >>= 1) acc += __shfl_down(acc, off, 64);
                    if (lane == 0) zsh[r] = acc + ((r < NJ) ? b_jump[r] : b_base[0]);
                }
                __syncthreads();

                if (tid == 0) {
                    const float* g = gumbel + ((size_t)n * BATCH + b) * NJ;
                    float m = -1e30f, mg = -1e30f; int jm = 0;
                    for (int r = 0; r < NJ; ++r) {
                        float z = zsh[r];
                        if (z > m) m = z;
                        float zg = z + g[r];
                        if (zg > mg) { mg = zg; jm = r; }   // strict > tiebreak
                    }
                    float s = 0.0f;
                    for (int r = 0; r < NJ; ++r) s += expf(zsh[r] - m);
                    float lse = m + logf(s);
                    int br = base_rows[b];
                    bool fp = (br + 20) >= LSEQ;
                    lp_arr[n * BATCH + b]   = fp ? 0.0f : (zsh[jm] - lse);
                    base_arr[n * BATCH + b] = zsh[41];
                    int reff = br + 20; if (reff > LSEQ - 1) reff = LSEQ - 1;
                    int nbr = (jm == 0) ? LSEQ : (reff + jm);
                    base_rows[b] = nbr;
                    rowsh = (nbr > LSEQ - 1) ? (LSEQ - 1) : nbr;
                }
                __syncthreads();

                if (n < 4) {                    // gather first x of next outer
                    int row = rowsh;
                    int tok = xs[(size_t)row * BATCH + b];
                    float ev = embW[(size_t)tok * EMBD + tid] *
                               mask[((size_t)row * BATCH + b) * EMBD + tid];
                    xcur[(size_t)b * KDIM + tid] = f2bf(ev);
                }
                grid.sync();
                br0 = base_rows[bcol_a];
                br1 = base_rows[bcol_b];
            }
        }
    }

    // ------------------------------- final ---------------------------------
    {
        int b = wg;
        const unsigned short* hp = xh + (size_t)p * XH + (size_t)b * KDIM + EMBD;
        union { short8x v; unsigned short u[8]; } hv;
        hv.v = *(const short8x*)(hp + lane * 8);
        float hf[8];
        #pragma unroll
        for (int j = 0; j < 8; ++j) hf[j] = bf2f(hv.u[j]);

        for (int r = w; r < 5; r += 4) {
            const float4* wp = (const float4*)(W_out + (size_t)r * HIDD + lane * 8);
            float4 w0 = wp[0], w1 = wp[1];
            float acc = w0.x*hf[0] + w0.y*hf[1] + w0.z*hf[2] + w0.w*hf[3]
                      + w1.x*hf[4] + w1.y*hf[5] + w1.z*hf[6] + w1.w*hf[7];
            #pragma unroll
            for (int off = 32; off > 0; off >>= 1) acc += __shfl_down(acc, off, 64);
            if (lane == 0) zsh[r] = acc + b_out[r];
        }
        __syncthreads();

        if (tid == 0) {
            float y[5];
            #pragma unroll
            for (int c = 0; c < 5; ++c) y[c] = zsh[c];
            float m = y[0]; int am = 0;
            for (int c = 1; c < 5; ++c) if (y[c] > m) { m = y[c]; am = c; }
            float s = 0.0f;
            for (int c = 0; c < 5; ++c) s += expf(y[c] - m);
            float lse = m + logf(s);
            int tb = tcls[b];
            float nll_p  = -(y[tb] - lse) * (1.0f / BATCH);
            float reward = (am == tb) ? 1.0f : -1.0f;
            float rp = 0.0f, mp = 0.0f;
            for (int nn = 0; nn < 5; ++nn) {
                float bs = base_arr[nn * BATCH + b];
                float lp = lp_arr[nn * BATCH + b];
                rp += -(reward - bs) * lp;
                float d = bs - reward;
                mp += d * d;
            }
            loss_arr[b] = nll_p + rp * (1.0f / (5.0f * BATCH)) + mp;
        }
    }
    grid.sync();
    if (wg == 0) {
        float* red = &gates[0][0];
        red[tid] = loss_arr[tid];
        __syncthreads();
        for (int off = 128; off > 0; off >>= 1) {
            if (tid < off) red[tid] += red[tid + off];
            __syncthreads();
        }
        if (tid == 0) out[0] = red[0];
    }
}

// ---------------------------------------------------------------------------
extern "C" void kernel_launch(void* const* d_in, const int* in_sizes, int n_in,
                              void* d_out, int out_size, void* d_ws, size_t ws_size,
                              hipStream_t stream)
{
    (void)in_sizes; (void)n_in; (void)out_size; (void)ws_size;
    const int*   xs     = (const int*)d_in[0];
    const int*   tcls   = (const int*)d_in[2];
    const float* embW   = (const float*)d_in[3];
    const float* W_ih   = (const float*)d_in[4];
    const float* W_hh   = (const float*)d_in[5];
    const float* b_ih   = (const float*)d_in[6];
    const float* b_hh   = (const float*)d_in[7];
    const float* W_out  = (const float*)d_in[8];
    const float* b_out  = (const float*)d_in[9];
    const float* W_jump = (const float*)d_in[10];
    const float* b_jump = (const float*)d_in[11];
    const float* W_base = (const float*)d_in[12];
    const float* b_base = (const float*)d_in[13];
    const float* mask   = (const float*)d_in[14];
    const float* gumbel = (const float*)d_in[15];

    char* w = (char*)d_ws;
    unsigned short* pW  = (unsigned short*)(w);                 // 3,145,728 B
    unsigned short* xh  = (unsigned short*)(w + 3145728);       //   786,432 B (2 buffers)
    int*   base_rows    = (int*)(w + 3932160);                  //     1,024 B
    float* lp_arr       = (float*)(w + 3933184);                //     5,120 B
    float* base_arr     = (float*)(w + 3938304);                //     5,120 B
    float* loss_arr     = (float*)(w + 3943424);                //     1,024 B
    float* outp         = (float*)d_out;

    prologue_kernel<<<256, 256, 0, stream>>>(W_ih, W_hh, xs, embW, mask,
                                             pW, xh, base_rows);

    void* args[] = {
        (void*)&pW, (void*)&xh, (void*)&base_rows,
        (void*)&b_ih, (void*)&b_hh, (void*)&xs, (void*)&embW, (void*)&mask,
        (void*)&W_jump, (void*)&b_jump, (void*)&W_base, (void*)&b_base,
        (void*)&gumbel, (void*)&lp_arr, (void*)&base_arr,
        (void*)&W_out, (void*)&b_out, (void*)&tcls,
        (void*)&loss_arr, (void*)&outp
    };
    hipLaunchCooperativeKernel((const void*)persistent_kernel,
                               dim3(256), dim3(256), args, 0, stream);
}

// Round 5
// 2685.878 us; speedup vs baseline: 1.4421x; 1.4421x over previous
//
#include <hip/hip_runtime.h>

#define LSEQ 400
#define BATCH 256
#define EMBD 256
#define HIDD 512
#define KDIM 768   // EMB + HID
#define NJ 41      // K+1
#define RLX __ATOMIC_RELAXED
#define AGT __HIP_MEMORY_SCOPE_AGENT

typedef __attribute__((ext_vector_type(8))) short short8x;
typedef __attribute__((ext_vector_type(4))) float f32x4;

__device__ __forceinline__ float bf2f(unsigned short u) {
    union { unsigned int i; float f; } v; v.i = ((unsigned int)u) << 16; return v.f;
}
__device__ __forceinline__ unsigned short f2bf(float f) {
    union { float f; unsigned int i; } v; v.f = f;
    unsigned int x = v.i;
    return (unsigned short)((x + 0x7fffu + ((x >> 16) & 1u)) >> 16);
}
__device__ __forceinline__ float sigm(float x) { return 1.0f / (1.0f + __expf(-x)); }

// Monotonic grid barrier. Semantics = cg::grid.sync() (release fence, arrive,
// spin, acquire fence) but: agent-scope fences (stop at L3, no HBM flush) and
// tight s_sleep(1) spin (cg's backoff sleep was ~36us/sync in R2).
__device__ __forceinline__ void gbar(unsigned* cnt, unsigned target) {
    __syncthreads();                       // all waves' stores drained to L2
    if (threadIdx.x == 0) {
        __threadfence();                   // release: wb dirty L2 -> L3
        __hip_atomic_fetch_add(cnt, 1u, RLX, AGT);
        while (__hip_atomic_load(cnt, RLX, AGT) < target)
            __builtin_amdgcn_s_sleep(1);
        __threadfence();                   // acquire: invalidate stale L1/L2
    }
    __syncthreads();
}

// ---------------------------------------------------------------------------
// Prologue: pack W_ih|W_hh (f32) into bf16 MFMA-fragment order; init state;
// reset barrier counter (replay-safe; agent-scope store -> lands at L3).
// pW layout: [gg(64)][mt(2)][kt(24)][lane(64)] x short8; row r=mt*16+(lane&15),
// gate=r>>3, hu=r&7, grow=gate*512+gg*8+hu, k=kt*32+(lane>>4)*8+j.
// ---------------------------------------------------------------------------
__global__ __launch_bounds__(256) void prologue_kernel(
    const float* __restrict__ W_ih, const float* __restrict__ W_hh,
    const int* __restrict__ xs, const float* __restrict__ embW,
    const float* __restrict__ mask,
    unsigned short* __restrict__ pW, unsigned short* __restrict__ xh0,
    float* __restrict__ c_st, int* __restrict__ base_rows,
    unsigned* __restrict__ cnt)
{
    int wg = blockIdx.x, t = threadIdx.x;
    int gg = wg >> 2, part = wg & 3;
    int lane = t & 63, sub = t >> 6;
    for (int q = 0; q < 3; ++q) {
        int f = sub * 3 + q;                 // 0..11
        int mt = f / 6, kt = part * 6 + (f % 6);
        int r = mt * 16 + (lane & 15);
        int gate = r >> 3, hu = r & 7;
        int grow = gate * 512 + gg * 8 + hu;
        int k0 = kt * 32 + ((lane >> 4) << 3);
        union { short8x v; unsigned short u[8]; } pk;
        #pragma unroll
        for (int j = 0; j < 8; ++j) {
            int k = k0 + j;
            float wv = (k < EMBD) ? W_ih[(size_t)grow * EMBD + k]
                                  : W_hh[(size_t)grow * HIDD + (k - EMBD)];
            pk.u[j] = f2bf(wv);
        }
        ((short8x*)pW)[((size_t)(gg * 2 + mt) * 24 + kt) * 64 + lane] = pk.v;
    }
    // per-batch state init (b = wg): x for step 0 (row 0), h=0, c=0, base=0
    int b = wg;
    int tok = xs[b];   // row 0
    float ev = embW[(size_t)tok * EMBD + t] * mask[(size_t)b * EMBD + t];
    xh0[(size_t)b * KDIM + t] = f2bf(ev);
    for (int e = t; e < HIDD; e += 256) {
        xh0[(size_t)b * KDIM + EMBD + e] = 0;
        c_st[(size_t)b * HIDD + e] = 0.0f;
    }
    if (t == 0) base_rows[b] = 0;
    if (wg == 0 && t == 0) __hip_atomic_store(cnt, 0u, RLX, AGT);
}

// ---------------------------------------------------------------------------
// Persistent kernel: all 105 steps + 5 boundaries + final. EXACT R2 data path
// (proven absmax 0): plain loads/stores, 4-wave mapping, Areg/c/h resident.
// Only change: gbar() instead of cg::grid.sync().
// ---------------------------------------------------------------------------
__global__ __launch_bounds__(256, 1) void persistent_kernel(
    const unsigned short* __restrict__ pW,
    unsigned short* __restrict__ xh,           // 2 double-buffered [256][768]
    int* __restrict__ base_rows,
    const float* __restrict__ b_ih, const float* __restrict__ b_hh,
    const int* __restrict__ xs, const float* __restrict__ embW,
    const float* __restrict__ mask,
    const float* __restrict__ W_jump, const float* __restrict__ b_jump,
    const float* __restrict__ W_base, const float* __restrict__ b_base,
    const float* __restrict__ gumbel,
    float* __restrict__ lp_arr, float* __restrict__ base_arr,
    const float* __restrict__ W_out, const float* __restrict__ b_out,
    const int* __restrict__ tcls,
    float* __restrict__ loss_arr, unsigned* __restrict__ cnt,
    float* __restrict__ out)
{
    __shared__ float gates[32][65];
    __shared__ __align__(16) unsigned short hstage[64][8];
    __shared__ float zsh[42];
    __shared__ int rowsh;

    const int wg = blockIdx.x;
    const int gg = wg >> 2, bg = wg & 3;
    const int tid = threadIdx.x, lane = tid & 63, w = tid >> 6;
    const int mhalf = w >> 1, npair = w & 1;

    // --- A fragments: registers for the whole sequence (24 x short8x) ---
    const short8x* Ab = ((const short8x*)pW) + ((size_t)(gg * 2 + mhalf) * 24) * 64 + lane;
    short8x Areg[24];
    #pragma unroll
    for (int kt = 0; kt < 24; ++kt) Areg[kt] = Ab[kt * 64];

    const int bcol0 = bg * 64 + npair * 32 + (lane & 15);
    const int krow  = (lane >> 4) << 3;

    // --- elementwise thread mapping: hu = tid>>5, two local cols ---
    const int hu  = tid >> 5;
    const int hid = gg * 8 + hu;
    const float bi  = b_ih[hid]        + b_hh[hid];
    const float bf_ = b_ih[512 + hid]  + b_hh[512 + hid];
    const float bgt = b_ih[1024 + hid] + b_hh[1024 + hid];
    const float bo  = b_ih[1536 + hid] + b_hh[1536 + hid];
    const int bl0 = (tid & 31) << 1;
    const int bcol_a = bg * 64 + bl0, bcol_b = bcol_a + 1;

    float c0 = 0.f, c1 = 0.f, h0 = 0.f, h1 = 0.f;   // resident LSTM state
    int br0 = 0, br1 = 0;                           // base rows for my 2 cols

    unsigned bar = 0;
    const size_t XH = (size_t)BATCH * KDIM;
    int p = 0;

    for (int n = 0; n < 5; ++n) {
        for (int i = 0; i <= 20; ++i) {
            const unsigned short* xin  = xh + (size_t)p * XH;
            unsigned short*       xout = xh + (size_t)(p ^ 1) * XH;
            const short8x* B0 = (const short8x*)(xin + (size_t)bcol0 * KDIM + krow);
            const short8x* B1 = (const short8x*)(xin + (size_t)(bcol0 + 16) * KDIM + krow);

            f32x4 acc0a = {0,0,0,0}, acc0b = {0,0,0,0};
            f32x4 acc1a = {0,0,0,0}, acc1b = {0,0,0,0};
            #pragma unroll
            for (int kt = 0; kt < 24; kt += 2) {
                short8x b00 = B0[kt * 4];
                short8x b01 = B0[(kt + 1) * 4];
                short8x b10 = B1[kt * 4];
                short8x b11 = B1[(kt + 1) * 4];
                acc0a = __builtin_amdgcn_mfma_f32_16x16x32_bf16(Areg[kt],     b00, acc0a, 0, 0, 0);
                acc1a = __builtin_amdgcn_mfma_f32_16x16x32_bf16(Areg[kt],     b10, acc1a, 0, 0, 0);
                acc0b = __builtin_amdgcn_mfma_f32_16x16x32_bf16(Areg[kt + 1], b01, acc0b, 0, 0, 0);
                acc1b = __builtin_amdgcn_mfma_f32_16x16x32_bf16(Areg[kt + 1], b11, acc1b, 0, 0, 0);
            }
            f32x4 acc0 = acc0a + acc0b, acc1 = acc1a + acc1b;

            int rbase = mhalf * 16 + ((lane >> 4) << 2);
            int cix   = npair * 32 + (lane & 15);
            #pragma unroll
            for (int v = 0; v < 4; ++v) {     // C/D map: col=lane&15, row=(lane>>4)*4+v
                gates[rbase + v][cix]      = acc0[v];
                gates[rbase + v][cix + 16] = acc1[v];
            }
            __syncthreads();

            // elementwise LSTM on resident state
            {
                bool fp = (br0 + i) >= LSEQ;
                float gi = gates[hu][bl0]      + bi;
                float gf = gates[8 + hu][bl0]  + bf_;
                float gc = gates[16 + hu][bl0] + bgt;
                float go = gates[24 + hu][bl0] + bo;
                float c2 = sigm(gf) * c0 + sigm(gi) * tanhf(gc);
                float h2 = sigm(go) * tanhf(c2);
                if (!fp) { c0 = c2; h0 = h2; }
                hstage[bl0][hu] = f2bf(h0);
            }
            {
                bool fp = (br1 + i) >= LSEQ;
                float gi = gates[hu][bl0 + 1]      + bi;
                float gf = gates[8 + hu][bl0 + 1]  + bf_;
                float gc = gates[16 + hu][bl0 + 1] + bgt;
                float go = gates[24 + hu][bl0 + 1] + bo;
                float c2 = sigm(gf) * c1 + sigm(gi) * tanhf(gc);
                float h2 = sigm(go) * tanhf(c2);
                if (!fp) { c1 = c2; h1 = h2; }
                hstage[bl0 + 1][hu] = f2bf(h1);
            }
            __syncthreads();
            if (tid < 64) {
                int b = bg * 64 + tid;
                short8x hv = *((const short8x*)&hstage[tid][0]);
                *((short8x*)(xout + (size_t)b * KDIM + EMBD + gg * 8)) = hv;
            }
            if (i < 20) {                      // fused gather of next x (b = wg)
                int b = wg;
                int br = base_rows[b];
                int row = br + i + 1; if (row > LSEQ - 1) row = LSEQ - 1;
                int tok = xs[(size_t)row * BATCH + b];
                float ev = embW[(size_t)tok * EMBD + tid] *
                           mask[((size_t)row * BATCH + b) * EMBD + tid];
                xout[(size_t)b * KDIM + tid] = f2bf(ev);
            }
            p ^= 1;
            gbar(cnt, (++bar) * 256u);

            if (i == 20) {
                // ---------------- boundary (one WG per batch elem) ----------
                unsigned short* xcur = xh + (size_t)p * XH;
                int b = wg;
                const unsigned short* hp = xcur + (size_t)b * KDIM + EMBD;
                union { short8x v; unsigned short u[8]; } hv;
                hv.v = *(const short8x*)(hp + lane * 8);
                float hf[8];
                #pragma unroll
                for (int j = 0; j < 8; ++j) hf[j] = bf2f(hv.u[j]);

                for (int r = w; r < 42; r += 4) {
                    const float* wr = (r < NJ) ? (W_jump + (size_t)r * HIDD) : W_base;
                    const float4* wp = (const float4*)(wr + lane * 8);
                    float4 w0 = wp[0], w1 = wp[1];
                    float acc = w0.x*hf[0] + w0.y*hf[1] + w0.z*hf[2] + w0.w*hf[3]
                              + w1.x*hf[4] + w1.y*hf[5] + w1.z*hf[6] + w1.w*hf[7];
                    #pragma unroll
                    for (int off = 32; off > 0; off >>= 1) acc += __shfl_down(acc, off, 64);
                    if (lane == 0) zsh[r] = acc + ((r < NJ) ? b_jump[r] : b_base[0]);
                }
                __syncthreads();

                if (tid == 0) {
                    const float* g = gumbel + ((size_t)n * BATCH + b) * NJ;
                    float m = -1e30f, mg = -1e30f; int jm = 0;
                    for (int r = 0; r < NJ; ++r) {
                        float z = zsh[r];
                        if (z > m) m = z;
                        float zg = z + g[r];
                        if (zg > mg) { mg = zg; jm = r; }   // strict > tiebreak
                    }
                    float s = 0.0f;
                    for (int r = 0; r < NJ; ++r) s += expf(zsh[r] - m);
                    float lse = m + logf(s);
                    int br = base_rows[b];
                    bool fp = (br + 20) >= LSEQ;
                    lp_arr[n * BATCH + b]   = fp ? 0.0f : (zsh[jm] - lse);
                    base_arr[n * BATCH + b] = zsh[41];
                    int reff = br + 20; if (reff > LSEQ - 1) reff = LSEQ - 1;
                    int nbr = (jm == 0) ? LSEQ : (reff + jm);
                    base_rows[b] = nbr;
                    rowsh = (nbr > LSEQ - 1) ? (LSEQ - 1) : nbr;
                }
                __syncthreads();

                if (n < 4) {                    // gather first x of next outer
                    int row = rowsh;
                    int tok = xs[(size_t)row * BATCH + b];
                    float ev = embW[(size_t)tok * EMBD + tid] *
                               mask[((size_t)row * BATCH + b) * EMBD + tid];
                    xcur[(size_t)b * KDIM + tid] = f2bf(ev);
                }
                gbar(cnt, (++bar) * 256u);
                br0 = base_rows[bcol_a];
                br1 = base_rows[bcol_b];
            }
        }
    }

    // ------------------------------- final ---------------------------------
    {
        int b = wg;
        const unsigned short* hp = xh + (size_t)p * XH + (size_t)b * KDIM + EMBD;
        union { short8x v; unsigned short u[8]; } hv;
        hv.v = *(const short8x*)(hp + lane * 8);
        float hf[8];
        #pragma unroll
        for (int j = 0; j < 8; ++j) hf[j] = bf2f(hv.u[j]);

        for (int r = w; r < 5; r += 4) {
            const float4* wp = (const float4*)(W_out + (size_t)r * HIDD + lane * 8);
            float4 w0 = wp[0], w1 = wp[1];
            float acc = w0.x*hf[0] + w0.y*hf[1] + w0.z*hf[2] + w0.w*hf[3]
                      + w1.x*hf[4] + w1.y*hf[5] + w1.z*hf[6] + w1.w*hf[7];
            #pragma unroll
            for (int off = 32; off > 0; off >>= 1) acc += __shfl_down(acc, off, 64);
            if (lane == 0) zsh[r] = acc + b_out[r];
        }
        __syncthreads();

        if (tid == 0) {
            float y[5];
            #pragma unroll
            for (int c = 0; c < 5; ++c) y[c] = zsh[c];
            float m = y[0]; int am = 0;
            for (int c = 1; c < 5; ++c) if (y[c] > m) { m = y[c]; am = c; }
            float s = 0.0f;
            for (int c = 0; c < 5; ++c) s += expf(y[c] - m);
            float lse = m + logf(s);
            int tb = tcls[b];
            float nll_p  = -(y[tb] - lse) * (1.0f / BATCH);
            float reward = (am == tb) ? 1.0f : -1.0f;
            float rp = 0.0f, mp = 0.0f;
            for (int nn = 0; nn < 5; ++nn) {
                float bs = base_arr[nn * BATCH + b];
                float lp = lp_arr[nn * BATCH + b];
                rp += -(reward - bs) * lp;
                float d = bs - reward;
                mp += d * d;
            }
            loss_arr[b] = nll_p + rp * (1.0f / (5.0f * BATCH)) + mp;
        }
    }
    gbar(cnt, (++bar) * 256u);
    if (wg == 0) {
        float* red = &gates[0][0];
        red[tid] = loss_arr[tid];
        __syncthreads();
        for (int off = 128; off > 0; off >>= 1) {
            if (tid < off) red[tid] += red[tid + off];
            __syncthreads();
        }
        if (tid == 0) out[0] = red[0];
    }
}

// ---------------------------------------------------------------------------
// Fallback path (R2-proven, used only if cooperative launch fails).
// ---------------------------------------------------------------------------
__global__ __launch_bounds__(256) void step_kernel(
    const unsigned short* __restrict__ pW,
    const unsigned short* __restrict__ xh_in,
    unsigned short* __restrict__ xh_out,
    float* __restrict__ c_st,
    const int* __restrict__ base_rows,
    const float* __restrict__ b_ih, const float* __restrict__ b_hh,
    const int* __restrict__ xs, const float* __restrict__ embW,
    const float* __restrict__ mask,
    int stepi, int do_gather)
{
    __shared__ float gates[32][65];
    __shared__ __align__(16) unsigned short hstage[64][8];

    int wg = blockIdx.x;
    int gg = wg >> 2, bg = wg & 3;
    int tid = threadIdx.x, lane = tid & 63, w = tid >> 6;
    int mhalf = w >> 1, npair = w & 1;

    const short8x* Ab = ((const short8x*)pW) + ((size_t)(gg * 2 + mhalf) * 24) * 64 + lane;
    int bcol0 = bg * 64 + npair * 32 + (lane & 15);
    int krow  = (lane >> 4) << 3;
    const short8x* B0 = (const short8x*)(xh_in + (size_t)bcol0 * KDIM + krow);
    const short8x* B1 = (const short8x*)(xh_in + (size_t)(bcol0 + 16) * KDIM + krow);

    f32x4 acc0a = {0,0,0,0}, acc0b = {0,0,0,0};
    f32x4 acc1a = {0,0,0,0}, acc1b = {0,0,0,0};
    #pragma unroll
    for (int kt = 0; kt < 24; kt += 2) {
        short8x a0  = Ab[kt * 64];
        short8x a1  = Ab[(kt + 1) * 64];
        short8x b00 = B0[kt * 4];
        short8x b01 = B0[(kt + 1) * 4];
        short8x b10 = B1[kt * 4];
        short8x b11 = B1[(kt + 1) * 4];
        acc0a = __builtin_amdgcn_mfma_f32_16x16x32_bf16(a0, b00, acc0a, 0, 0, 0);
        acc1a = __builtin_amdgcn_mfma_f32_16x16x32_bf16(a0, b10, acc1a, 0, 0, 0);
        acc0b = __builtin_amdgcn_mfma_f32_16x16x32_bf16(a1, b01, acc0b, 0, 0, 0);
        acc1b = __builtin_amdgcn_mfma_f32_16x16x32_bf16(a1, b11, acc1b, 0, 0, 0);
    }
    f32x4 acc0 = acc0a + acc0b, acc1 = acc1a + acc1b;

    int rbase = mhalf * 16 + ((lane >> 4) << 2);
    int cix   = npair * 32 + (lane & 15);
    #pragma unroll
    for (int v = 0; v < 4; ++v) {
        gates[rbase + v][cix]      = acc0[v];
        gates[rbase + v][cix + 16] = acc1[v];
    }
    __syncthreads();

    int hu  = tid >> 5;
    int hid = gg * 8 + hu;
    float bi  = b_ih[hid]        + b_hh[hid];
    float bf_ = b_ih[512 + hid]  + b_hh[512 + hid];
    float bgt = b_ih[1024 + hid] + b_hh[1024 + hid];
    float bo  = b_ih[1536 + hid] + b_hh[1536 + hid];
    #pragma unroll
    for (int u = 0; u < 2; ++u) {
        int bl = ((tid & 31) << 1) + u;
        int b  = bg * 64 + bl;
        int br = base_rows[b];
        bool fp = (br + stepi) >= LSEQ;
        float gi = gates[hu][bl]      + bi;
        float gf = gates[8 + hu][bl]  + bf_;
        float gc = gates[16 + hu][bl] + bgt;
        float go = gates[24 + hu][bl] + bo;
        float cold = c_st[(size_t)b * HIDD + hid];
        float c2 = sigm(gf) * cold + sigm(gi) * tanhf(gc);
        float h2 = sigm(go) * tanhf(c2);
        unsigned short hb;
        if (fp) {
            hb = xh_in[(size_t)b * KDIM + EMBD + hid];
        } else {
            hb = f2bf(h2);
            c_st[(size_t)b * HIDD + hid] = c2;
        }
        hstage[bl][hu] = hb;
    }
    __syncthreads();
    if (tid < 64) {
        int b = bg * 64 + tid;
        short8x hv = *((const short8x*)&hstage[tid][0]);
        *((short8x*)(xh_out + (size_t)b * KDIM + EMBD + gg * 8)) = hv;
    }
    if (do_gather) {
        int b = wg;
        int br = base_rows[b];
        int row = br + stepi + 1; if (row > LSEQ - 1) row = LSEQ - 1;
        int tok = xs[(size_t)row * BATCH + b];
        float ev = embW[(size_t)tok * EMBD + tid] *
                   mask[((size_t)row * BATCH + b) * EMBD + tid];
        xh_out[(size_t)b * KDIM + tid] = f2bf(ev);
    }
}

__global__ __launch_bounds__(256) void boundary_kernel(
    unsigned short* xh,
    int* __restrict__ base_rows,
    const float* __restrict__ W_jump, const float* __restrict__ b_jump,
    const float* __restrict__ W_base, const float* __restrict__ b_base,
    const float* __restrict__ gumbel,
    float* __restrict__ lp_arr, float* __restrict__ base_arr,
    const int* __restrict__ xs, const float* __restrict__ embW,
    const float* __restrict__ mask,
    int n, int do_gather)
{
    __shared__ float zsh[42];
    __shared__ int rowsh;
    int b = blockIdx.x;
    int tid = threadIdx.x, lane = tid & 63, w = tid >> 6;

    const unsigned short* hp = xh + (size_t)b * KDIM + EMBD;
    union { short8x v; unsigned short u[8]; } hv;
    hv.v = *(const short8x*)(hp + lane * 8);
    float hf[8];
    #pragma unroll
    for (int j = 0; j < 8; ++j) hf[j] = bf2f(hv.u[j]);

    for (int r = w; r < 42; r += 4) {
        const float* wr = (r < NJ) ? (W_jump + (size_t)r * HIDD) : W_base;
        const float4* wp = (const float4*)(wr + lane * 8);
        float4 w0 = wp[0], w1 = wp[1];
        float acc = w0.x*hf[0] + w0.y*hf[1] + w0.z*hf[2] + w0.w*hf[3]
                  + w1.x*hf[4] + w1.y*hf[5] + w1.z*hf[6] + w1.w*hf[7];
        #pragma unroll
        for (int off = 32; off > 0; off >>= 1) acc += __shfl_down(acc, off, 64);
        if (lane == 0) zsh[r] = acc + ((r < NJ) ? b_jump[r] : b_base[0]);
    }
    __syncthreads();

    if (tid == 0) {
        const float* g = gumbel + ((size_t)n * BATCH + b) * NJ;
        float m = -1e30f, mg = -1e30f; int jm = 0;
        for (int r = 0; r < NJ; ++r) {
            float z = zsh[r];
            if (z > m) m = z;
            float zg = z + g[r];
            if (zg > mg) { mg = zg; jm = r; }
        }
        float s = 0.0f;
        for (int r = 0; r < NJ; ++r) s += expf(zsh[r] - m);
        float lse = m + logf(s);
        int br = base_rows[b];
        bool fp = (br + 20) >= LSEQ;
        lp_arr[n * BATCH + b]   = fp ? 0.0f : (zsh[jm] - lse);
        base_arr[n * BATCH + b] = zsh[41];
        int reff = br + 20; if (reff > LSEQ - 1) reff = LSEQ - 1;
        int nbr = (jm == 0) ? LSEQ : (reff + jm);
        base_rows[b] = nbr;
        rowsh = (nbr > LSEQ - 1) ? (LSEQ - 1) : nbr;
    }
    __syncthreads();

    if (do_gather) {
        int row = rowsh;
        int tok = xs[(size_t)row * BATCH + b];
        float ev = embW[(size_t)tok * EMBD + tid] *
                   mask[((size_t)row * BATCH + b) * EMBD + tid];
        xh[(size_t)b * KDIM + tid] = f2bf(ev);
    }
}

__global__ __launch_bounds__(256) void final_kernel(
    const unsigned short* __restrict__ xh,
    const float* __restrict__ W_out, const float* __restrict__ b_out,
    const int* __restrict__ tcls,
    const float* __restrict__ lp_arr, const float* __restrict__ base_arr,
    float* __restrict__ out)
{
    __shared__ float red[256];
    int b = threadIdx.x;
    const unsigned short* hp = xh + (size_t)b * KDIM + EMBD;
    float y[5];
    for (int c = 0; c < 5; ++c) {
        const float* wr = W_out + (size_t)c * HIDD;
        float acc = 0.0f;
        for (int k = 0; k < HIDD; k += 8) {
            union { short8x v; unsigned short u[8]; } hv;
            hv.v = *(const short8x*)(hp + k);
            #pragma unroll
            for (int j = 0; j < 8; ++j) acc += wr[k + j] * bf2f(hv.u[j]);
        }
        y[c] = acc + b_out[c];
    }
    float m = y[0]; int am = 0;
    for (int c = 1; c < 5; ++c) if (y[c] > m) { m = y[c]; am = c; }
    float s = 0.0f;
    for (int c = 0; c < 5; ++c) s += expf(y[c] - m);
    float lse = m + logf(s);
    int tb = tcls[b];
    float nll_p  = -(y[tb] - lse) * (1.0f / BATCH);
    float reward = (am == tb) ? 1.0f : -1.0f;
    float rp = 0.0f, mp = 0.0f;
    for (int nn = 0; nn < 5; ++nn) {
        float bs = base_arr[nn * BATCH + b];
        float lp = lp_arr[nn * BATCH + b];
        rp += -(reward - bs) * lp;
        float d = bs - reward;
        mp += d * d;
    }
    red[b] = nll_p + rp * (1.0f / (5.0f * BATCH)) + mp;
    __syncthreads();
    for (int off = 128; off > 0; off >>= 1) {
        if (b < off) red[b] += red[b + off];
        __syncthreads();
    }
    if (b == 0) out[0] = red[0];
}

// ---------------------------------------------------------------------------
extern "C" void kernel_launch(void* const* d_in, const int* in_sizes, int n_in,
                              void* d_out, int out_size, void* d_ws, size_t ws_size,
                              hipStream_t stream)
{
    (void)in_sizes; (void)n_in; (void)out_size; (void)ws_size;
    const int*   xs     = (const int*)d_in[0];
    const int*   tcls   = (const int*)d_in[2];
    const float* embW   = (const float*)d_in[3];
    const float* W_ih   = (const float*)d_in[4];
    const float* W_hh   = (const float*)d_in[5];
    const float* b_ih   = (const float*)d_in[6];
    const float* b_hh   = (const float*)d_in[7];
    const float* W_out  = (const float*)d_in[8];
    const float* b_out  = (const float*)d_in[9];
    const float* W_jump = (const float*)d_in[10];
    const float* b_jump = (const float*)d_in[11];
    const float* W_base = (const float*)d_in[12];
    const float* b_base = (const float*)d_in[13];
    const float* mask   = (const float*)d_in[14];
    const float* gumbel = (const float*)d_in[15];

    char* wsp = (char*)d_ws;
    unsigned short* pW  = (unsigned short*)(wsp);                 // 3,145,728 B
    unsigned short* xh  = (unsigned short*)(wsp + 3145728);       //   786,432 B
    float*    c_st      = (float*)(wsp + 3932160);                //   524,288 B (fallback)
    int*      base_rows = (int*)(wsp + 4456448);                  //     1,024 B
    float*    lp_arr    = (float*)(wsp + 4457472);                //     5,120 B
    float*    base_arr  = (float*)(wsp + 4462592);                //     5,120 B
    float*    loss_arr  = (float*)(wsp + 4467712);                //     1,024 B
    unsigned* cnt       = (unsigned*)(wsp + 4468736);             //        64 B
    float*    outp      = (float*)d_out;

    const size_t XH = (size_t)BATCH * KDIM;

    prologue_kernel<<<256, 256, 0, stream>>>(W_ih, W_hh, xs, embW, mask,
                                             pW, xh, c_st, base_rows, cnt);

    void* args[] = {
        (void*)&pW, (void*)&xh, (void*)&base_rows,
        (void*)&b_ih, (void*)&b_hh, (void*)&xs, (void*)&embW, (void*)&mask,
        (void*)&W_jump, (void*)&b_jump, (void*)&W_base, (void*)&b_base,
        (void*)&gumbel, (void*)&lp_arr, (void*)&base_arr,
        (void*)&W_out, (void*)&b_out, (void*)&tcls,
        (void*)&loss_arr, (void*)&cnt, (void*)&outp
    };
    hipError_t err = hipLaunchCooperativeKernel((const void*)persistent_kernel,
                                                dim3(256), dim3(256), args, 0, stream);
    if (err != hipSuccess) {
        // Fallback: proven multi-kernel path (R2).
        int p = 0;
        for (int s = 0; s < 105; ++s) {
            int i = s % 21;
            step_kernel<<<256, 256, 0, stream>>>(pW, xh + (size_t)p * XH,
                                                 xh + (size_t)(p ^ 1) * XH,
                                                 c_st, base_rows, b_ih, b_hh,
                                                 xs, embW, mask, i, (i < 20) ? 1 : 0);
            p ^= 1;
            if (i == 20) {
                int n = s / 21;
                boundary_kernel<<<256, 256, 0, stream>>>(xh + (size_t)p * XH, base_rows,
                                                         W_jump, b_jump, W_base, b_base,
                                                         gumbel, lp_arr, base_arr,
                                                         xs, embW, mask,
                                                         n, (n < 4) ? 1 : 0);
            }
        }
        final_kernel<<<1, 256, 0, stream>>>(xh + (size_t)p * XH, W_out, b_out, tcls,
                                            lp_arr, base_arr, outp);
    }
}

// Round 6
// 1626.986 us; speedup vs baseline: 2.3806x; 1.6508x over previous
//
#include <hip/hip_runtime.h>

#define LSEQ 400
#define BATCH 256
#define EMBD 256
#define HIDD 512
#define KDIM 768   // EMB + HID
#define NJ 41      // K+1
#define RLX __ATOMIC_RELAXED
#define AGT __HIP_MEMORY_SCOPE_AGENT

typedef __attribute__((ext_vector_type(8))) short short8x;
typedef __attribute__((ext_vector_type(4))) float f32x4;
typedef unsigned long long u64;

union BQ { short8x v; unsigned short u[8]; u64 q[2]; };

__device__ __forceinline__ float bf2f(unsigned short u) {
    union { unsigned int i; float f; } v; v.i = ((unsigned int)u) << 16; return v.f;
}
__device__ __forceinline__ unsigned short f2bf(float f) {
    union { float f; unsigned int i; } v; v.f = f;
    unsigned int x = v.i;
    return (unsigned short)((x + 0x7fffu + ((x >> 16) & 1u)) >> 16);
}
__device__ __forceinline__ float sigm(float x) { return 1.0f / (1.0f + __expf(-x)); }

__device__ __forceinline__ u64 ald(const u64* p) {
    return __hip_atomic_load((u64*)p, RLX, AGT);
}
__device__ __forceinline__ void ast(u64* p, u64 v) {
    __hip_atomic_store(p, v, RLX, AGT);
}

// Contention-free grid barrier: per-WG padded arrival flags (one agent store
// each, distinct cachelines) + master WG (256 threads poll 256 flags) + one
// 'go' broadcast word. No fences: cross-WG data moves via sc1 atomics (L3),
// so L2 never needs writeback/invalidate and stays warm for read-only data.
// vmcnt(0) orders this WG's data stores before its arrival store.
__device__ __forceinline__ void gbar(unsigned* flags, unsigned* go, unsigned bar) {
    asm volatile("s_waitcnt vmcnt(0) lgkmcnt(0)" ::: "memory");
    __syncthreads();
    const int tid = threadIdx.x;
    if (blockIdx.x == 0) {
        if (tid == 0) __hip_atomic_store(&flags[0], bar, RLX, AGT);
        while (__hip_atomic_load(&flags[(unsigned)tid * 32u], RLX, AGT) < bar)
            __builtin_amdgcn_s_sleep(1);
        __syncthreads();
        if (tid == 0) __hip_atomic_store(go, bar, RLX, AGT);
    } else {
        if (tid == 0) {
            __hip_atomic_store(&flags[(unsigned)blockIdx.x * 32u], bar, RLX, AGT);
            while (__hip_atomic_load(go, RLX, AGT) < bar)
                __builtin_amdgcn_s_sleep(1);
        }
        __syncthreads();
    }
}

// ---------------------------------------------------------------------------
// Prologue: pack W_ih|W_hh (f32) into bf16 MFMA-fragment order; init state;
// zero barrier flags+go (replay-safe; kernel-end release makes it visible).
// pW layout: [gg(64)][mt(2)][kt(24)][lane(64)] x short8; row r=mt*16+(lane&15),
// gate=r>>3, hu=r&7, grow=gate*512+gg*8+hu, k=kt*32+(lane>>4)*8+j.
// ---------------------------------------------------------------------------
__global__ __launch_bounds__(256) void prologue_kernel(
    const float* __restrict__ W_ih, const float* __restrict__ W_hh,
    const int* __restrict__ xs, const float* __restrict__ embW,
    const float* __restrict__ mask,
    unsigned short* __restrict__ pW, unsigned short* __restrict__ xh0,
    float* __restrict__ c_st, int* __restrict__ base_rows,
    unsigned* __restrict__ flags, unsigned* __restrict__ go)
{
    int wg = blockIdx.x, t = threadIdx.x;
    int gg = wg >> 2, part = wg & 3;
    int lane = t & 63, sub = t >> 6;
    for (int q = 0; q < 3; ++q) {
        int f = sub * 3 + q;                 // 0..11
        int mt = f / 6, kt = part * 6 + (f % 6);
        int r = mt * 16 + (lane & 15);
        int gate = r >> 3, hu = r & 7;
        int grow = gate * 512 + gg * 8 + hu;
        int k0 = kt * 32 + ((lane >> 4) << 3);
        union { short8x v; unsigned short u[8]; } pk;
        #pragma unroll
        for (int j = 0; j < 8; ++j) {
            int k = k0 + j;
            float wv = (k < EMBD) ? W_ih[(size_t)grow * EMBD + k]
                                  : W_hh[(size_t)grow * HIDD + (k - EMBD)];
            pk.u[j] = f2bf(wv);
        }
        ((short8x*)pW)[((size_t)(gg * 2 + mt) * 24 + kt) * 64 + lane] = pk.v;
    }
    // per-batch state init (b = wg): x for step 0 (row 0), h=0, c=0, base=0
    int b = wg;
    int tok = xs[b];   // row 0
    float ev = embW[(size_t)tok * EMBD + t] * mask[(size_t)b * EMBD + t];
    xh0[(size_t)b * KDIM + t] = f2bf(ev);
    for (int e = t; e < HIDD; e += 256) {
        xh0[(size_t)b * KDIM + EMBD + e] = 0;
        c_st[(size_t)b * HIDD + e] = 0.0f;
    }
    if (t == 0) base_rows[b] = 0;
    if (wg == 0) {
        flags[t * 32] = 0u;
        if (t == 0) go[0] = 0u;
    }
}

// ---------------------------------------------------------------------------
// Persistent kernel: all 105 steps + 5 boundaries + final. R5's proven data
// path & wave mapping; cross-WG traffic now via sc1 atomics + flags barrier.
// ---------------------------------------------------------------------------
__global__ __launch_bounds__(256, 1) void persistent_kernel(
    const unsigned short* __restrict__ pW,
    unsigned short* __restrict__ xh,           // 2 double-buffered [256][768]
    int* __restrict__ base_rows,
    const float* __restrict__ b_ih, const float* __restrict__ b_hh,
    const int* __restrict__ xs, const float* __restrict__ embW,
    const float* __restrict__ mask,
    const float* __restrict__ W_jump, const float* __restrict__ b_jump,
    const float* __restrict__ W_base, const float* __restrict__ b_base,
    const float* __restrict__ gumbel,
    float* __restrict__ lp_arr, float* __restrict__ base_arr,
    const float* __restrict__ W_out, const float* __restrict__ b_out,
    const int* __restrict__ tcls,
    float* __restrict__ loss_arr,
    unsigned* __restrict__ flags, unsigned* __restrict__ go,
    float* __restrict__ out)
{
    __shared__ float gates[32][65];
    __shared__ __align__(16) unsigned short hstage[64][8];
    __shared__ __align__(8)  unsigned short xg[256];
    __shared__ float zsh[42];
    __shared__ int rowsh, nbrsh;

    const int wg = blockIdx.x;
    const int gg = wg >> 2, bg = wg & 3;
    const int tid = threadIdx.x, lane = tid & 63, w = tid >> 6;
    const int mhalf = w >> 1, npair = w & 1;

    // --- A fragments: registers for the whole sequence (24 x short8x) ---
    const short8x* Ab = ((const short8x*)pW) + ((size_t)(gg * 2 + mhalf) * 24) * 64 + lane;
    short8x Areg[24];
    #pragma unroll
    for (int kt = 0; kt < 24; ++kt) Areg[kt] = Ab[kt * 64];

    const int bcol0 = bg * 64 + npair * 32 + (lane & 15);
    const int krow  = (lane >> 4) << 3;

    // --- elementwise thread mapping: hu = tid>>5, two local cols ---
    const int hu  = tid >> 5;
    const int hid = gg * 8 + hu;
    const float bi  = b_ih[hid]        + b_hh[hid];
    const float bf_ = b_ih[512 + hid]  + b_hh[512 + hid];
    const float bgt = b_ih[1024 + hid] + b_hh[1024 + hid];
    const float bo  = b_ih[1536 + hid] + b_hh[1536 + hid];
    const int bl0 = (tid & 31) << 1;
    const int bcol_a = bg * 64 + bl0, bcol_b = bcol_a + 1;

    float c0 = 0.f, c1 = 0.f, h0 = 0.f, h1 = 0.f;   // resident LSTM state
    int br0 = 0, br1 = 0, rowg = 0;                 // base rows (regs, refreshed per boundary)

    unsigned bar = 0;
    const size_t XH = (size_t)BATCH * KDIM;
    int p = 0;

    for (int n = 0; n < 5; ++n) {
        for (int i = 0; i <= 20; ++i) {
            const unsigned short* xin  = xh + (size_t)p * XH;
            unsigned short*       xout = xh + (size_t)(p ^ 1) * XH;

            // issue gather loads early (plain: embW/mask/xs are read-only, L2-warm)
            float ge = 0.f, gm = 0.f;
            if (i < 20) {
                int row = rowg + i + 1; if (row > LSEQ - 1) row = LSEQ - 1;
                int tok = xs[(size_t)row * BATCH + wg];
                ge = embW[(size_t)tok * EMBD + tid];
                gm = mask[((size_t)row * BATCH + wg) * EMBD + tid];
            }

            // B loads (sc1: cross-WG data) + MFMA
            const u64* Bq0 = (const u64*)(xin + (size_t)bcol0 * KDIM + krow);
            const u64* Bq1 = (const u64*)(xin + (size_t)(bcol0 + 16) * KDIM + krow);
            f32x4 acc0a = {0,0,0,0}, acc0b = {0,0,0,0};
            f32x4 acc1a = {0,0,0,0}, acc1b = {0,0,0,0};
            #pragma unroll
            for (int kt = 0; kt < 24; kt += 2) {
                BQ b00, b01, b10, b11;
                b00.q[0] = ald(Bq0 + (size_t)kt * 8);
                b00.q[1] = ald(Bq0 + (size_t)kt * 8 + 1);
                b10.q[0] = ald(Bq1 + (size_t)kt * 8);
                b10.q[1] = ald(Bq1 + (size_t)kt * 8 + 1);
                b01.q[0] = ald(Bq0 + (size_t)(kt + 1) * 8);
                b01.q[1] = ald(Bq0 + (size_t)(kt + 1) * 8 + 1);
                b11.q[0] = ald(Bq1 + (size_t)(kt + 1) * 8);
                b11.q[1] = ald(Bq1 + (size_t)(kt + 1) * 8 + 1);
                acc0a = __builtin_amdgcn_mfma_f32_16x16x32_bf16(Areg[kt],     b00.v, acc0a, 0, 0, 0);
                acc1a = __builtin_amdgcn_mfma_f32_16x16x32_bf16(Areg[kt],     b10.v, acc1a, 0, 0, 0);
                acc0b = __builtin_amdgcn_mfma_f32_16x16x32_bf16(Areg[kt + 1], b01.v, acc0b, 0, 0, 0);
                acc1b = __builtin_amdgcn_mfma_f32_16x16x32_bf16(Areg[kt + 1], b11.v, acc1b, 0, 0, 0);
            }
            f32x4 acc0 = acc0a + acc0b, acc1 = acc1a + acc1b;

            int rbase = mhalf * 16 + ((lane >> 4) << 2);
            int cix   = npair * 32 + (lane & 15);
            #pragma unroll
            for (int v = 0; v < 4; ++v) {     // C/D map: col=lane&15, row=(lane>>4)*4+v
                gates[rbase + v][cix]      = acc0[v];
                gates[rbase + v][cix + 16] = acc1[v];
            }
            __syncthreads();

            // elementwise LSTM on resident state
            {
                bool fp = (br0 + i) >= LSEQ;
                float gi = gates[hu][bl0]      + bi;
                float gf = gates[8 + hu][bl0]  + bf_;
                float gc = gates[16 + hu][bl0] + bgt;
                float go_ = gates[24 + hu][bl0] + bo;
                float c2 = sigm(gf) * c0 + sigm(gi) * tanhf(gc);
                float h2 = sigm(go_) * tanhf(c2);
                if (!fp) { c0 = c2; h0 = h2; }
                hstage[bl0][hu] = f2bf(h0);
            }
            {
                bool fp = (br1 + i) >= LSEQ;
                float gi = gates[hu][bl0 + 1]      + bi;
                float gf = gates[8 + hu][bl0 + 1]  + bf_;
                float gc = gates[16 + hu][bl0 + 1] + bgt;
                float go_ = gates[24 + hu][bl0 + 1] + bo;
                float c2 = sigm(gf) * c1 + sigm(gi) * tanhf(gc);
                float h2 = sigm(go_) * tanhf(c2);
                if (!fp) { c1 = c2; h1 = h2; }
                hstage[bl0 + 1][hu] = f2bf(h1);
            }
            if (i < 20) xg[tid] = f2bf(ge * gm);
            __syncthreads();

            // sc1 stores: h slice (all WGs) + next x (owner WG, staged via xg)
            if (tid < 64) {
                const u64* hp = (const u64*)&hstage[tid][0];
                u64* dst = (u64*)(xout + (size_t)(bg * 64 + tid) * KDIM + EMBD + gg * 8);
                ast(dst,     hp[0]);
                ast(dst + 1, hp[1]);
                if (i < 20) {
                    u64 xv = ((const u64*)xg)[tid];
                    ast((u64*)(xout + (size_t)wg * KDIM) + tid, xv);
                }
            }
            p ^= 1;
            gbar(flags, go, ++bar);

            if (i == 20) {
                // ---------------- boundary (one WG per batch elem) ----------
                unsigned short* xcur = xh + (size_t)p * XH;
                BQ hv;
                const u64* hq = (const u64*)(xcur + (size_t)wg * KDIM + EMBD) + lane * 2;
                hv.q[0] = ald(hq);
                hv.q[1] = ald(hq + 1);
                float hf[8];
                #pragma unroll
                for (int q = 0; q < 8; ++q) hf[q] = bf2f(hv.u[q]);

                for (int r = w; r < 42; r += 4) {
                    const float* wr = (r < NJ) ? (W_jump + (size_t)r * HIDD) : W_base;
                    const float4* wp = (const float4*)(wr + lane * 8);
                    float4 w0 = wp[0], w1 = wp[1];
                    float acc = w0.x*hf[0] + w0.y*hf[1] + w0.z*hf[2] + w0.w*hf[3]
                              + w1.x*hf[4] + w1.y*hf[5] + w1.z*hf[6] + w1.w*hf[7];
                    #pragma unroll
                    for (int off = 32; off > 0; off >>= 1) acc += __shfl_down(acc, off, 64);
                    if (lane == 0) zsh[r] = acc + ((r < NJ) ? b_jump[r] : b_base[0]);
                }
                __syncthreads();

                if (tid == 0) {
                    const float* g = gumbel + ((size_t)n * BATCH + wg) * NJ;
                    float m = -1e30f, mg = -1e30f; int jm = 0;
                    for (int r = 0; r < NJ; ++r) {
                        float z = zsh[r];
                        if (z > m) m = z;
                        float zg = z + g[r];
                        if (zg > mg) { mg = zg; jm = r; }   // strict > tiebreak
                    }
                    float s = 0.0f;
                    for (int r = 0; r < NJ; ++r) s += expf(zsh[r] - m);
                    float lse = m + logf(s);
                    int br = rowg;                         // own base row (register)
                    bool fp = (br + 20) >= LSEQ;
                    lp_arr[n * BATCH + wg]   = fp ? 0.0f : (zsh[jm] - lse);   // plain: same-WG consumer
                    base_arr[n * BATCH + wg] = zsh[41];
                    int reff = br + 20; if (reff > LSEQ - 1) reff = LSEQ - 1;
                    int nbr = (jm == 0) ? LSEQ : (reff + jm);
                    __hip_atomic_store(&base_rows[wg], nbr, RLX, AGT);
                    nbrsh = nbr;
                    rowsh = (nbr > LSEQ - 1) ? (LSEQ - 1) : nbr;
                }
                __syncthreads();

                if (n < 4) {                    // gather first x of next outer
                    int row = rowsh;
                    int tok = xs[(size_t)row * BATCH + wg];
                    float ev = embW[(size_t)tok * EMBD + tid] *
                               mask[((size_t)row * BATCH + wg) * EMBD + tid];
                    xg[tid] = f2bf(ev);
                }
                __syncthreads();
                if (n < 4 && tid < 64) {
                    u64 xv = ((const u64*)xg)[tid];
                    ast((u64*)(xcur + (size_t)wg * KDIM) + tid, xv);
                }
                rowg = nbrsh;
                gbar(flags, go, ++bar);
                br0 = __hip_atomic_load(&base_rows[bcol_a], RLX, AGT);
                br1 = __hip_atomic_load(&base_rows[bcol_b], RLX, AGT);
            }
        }
    }

    // ------------------------------- final ---------------------------------
    {
        const unsigned short* xcur = xh + (size_t)p * XH;
        BQ hv;
        const u64* hq = (const u64*)(xcur + (size_t)wg * KDIM + EMBD) + lane * 2;
        hv.q[0] = ald(hq);
        hv.q[1] = ald(hq + 1);
        float hf[8];
        #pragma unroll
        for (int q = 0; q < 8; ++q) hf[q] = bf2f(hv.u[q]);

        for (int r = w; r < 5; r += 4) {
            const float4* wp = (const float4*)(W_out + (size_t)r * HIDD + lane * 8);
            float4 w0 = wp[0], w1 = wp[1];
            float acc = w0.x*hf[0] + w0.y*hf[1] + w0.z*hf[2] + w0.w*hf[3]
                      + w1.x*hf[4] + w1.y*hf[5] + w1.z*hf[6] + w1.w*hf[7];
            #pragma unroll
            for (int off = 32; off > 0; off >>= 1) acc += __shfl_down(acc, off, 64);
            if (lane == 0) zsh[r] = acc + b_out[r];
        }
        __syncthreads();

        if (tid == 0) {
            float y[5];
            #pragma unroll
            for (int c = 0; c < 5; ++c) y[c] = zsh[c];
            float m = y[0]; int am = 0;
            for (int c = 1; c < 5; ++c) if (y[c] > m) { m = y[c]; am = c; }
            float s = 0.0f;
            for (int c = 0; c < 5; ++c) s += expf(y[c] - m);
            float lse = m + logf(s);
            int tb = tcls[wg];
            float nll_p  = -(y[tb] - lse) * (1.0f / BATCH);
            float reward = (am == tb) ? 1.0f : -1.0f;
            float rp = 0.0f, mp = 0.0f;
            for (int nn = 0; nn < 5; ++nn) {
                float bs = base_arr[nn * BATCH + wg];
                float lp = lp_arr[nn * BATCH + wg];
                rp += -(reward - bs) * lp;
                float d = bs - reward;
                mp += d * d;
            }
            float loss = nll_p + rp * (1.0f / (5.0f * BATCH)) + mp;
            __hip_atomic_store(&loss_arr[wg], loss, RLX, AGT);
        }
    }
    gbar(flags, go, ++bar);
    if (wg == 0) {
        float* red = &gates[0][0];
        red[tid] = __hip_atomic_load(&loss_arr[tid], RLX, AGT);
        __syncthreads();
        for (int off = 128; off > 0; off >>= 1) {
            if (tid < off) red[tid] += red[tid + off];
            __syncthreads();
        }
        if (tid == 0) out[0] = red[0];
    }
}

// ---------------------------------------------------------------------------
// Fallback path (R2-proven, used only if cooperative launch fails).
// ---------------------------------------------------------------------------
__global__ __launch_bounds__(256) void step_kernel(
    const unsigned short* __restrict__ pW,
    const unsigned short* __restrict__ xh_in,
    unsigned short* __restrict__ xh_out,
    float* __restrict__ c_st,
    const int* __restrict__ base_rows,
    const float* __restrict__ b_ih, const float* __restrict__ b_hh,
    const int* __restrict__ xs, const float* __restrict__ embW,
    const float* __restrict__ mask,
    int stepi, int do_gather)
{
    __shared__ float gates[32][65];
    __shared__ __align__(16) unsigned short hstage[64][8];

    int wg = blockIdx.x;
    int gg = wg >> 2, bg = wg & 3;
    int tid = threadIdx.x, lane = tid & 63, w = tid >> 6;
    int mhalf = w >> 1, npair = w & 1;

    const short8x* Ab = ((const short8x*)pW) + ((size_t)(gg * 2 + mhalf) * 24) * 64 + lane;
    int bcol0 = bg * 64 + npair * 32 + (lane & 15);
    int krow  = (lane >> 4) << 3;
    const short8x* B0 = (const short8x*)(xh_in + (size_t)bcol0 * KDIM + krow);
    const short8x* B1 = (const short8x*)(xh_in + (size_t)(bcol0 + 16) * KDIM + krow);

    f32x4 acc0a = {0,0,0,0}, acc0b = {0,0,0,0};
    f32x4 acc1a = {0,0,0,0}, acc1b = {0,0,0,0};
    #pragma unroll
    for (int kt = 0; kt < 24; kt += 2) {
        short8x a0  = Ab[kt * 64];
        short8x a1  = Ab[(kt + 1) * 64];
        short8x b00 = B0[kt * 4];
        short8x b01 = B0[(kt + 1) * 4];
        short8x b10 = B1[kt * 4];
        short8x b11 = B1[(kt + 1) * 4];
        acc0a = __builtin_amdgcn_mfma_f32_16x16x32_bf16(a0, b00, acc0a, 0, 0, 0);
        acc1a = __builtin_amdgcn_mfma_f32_16x16x32_bf16(a0, b10, acc1a, 0, 0, 0);
        acc0b = __builtin_amdgcn_mfma_f32_16x16x32_bf16(a1, b01, acc0b, 0, 0, 0);
        acc1b = __builtin_amdgcn_mfma_f32_16x16x32_bf16(a1, b11, acc1b, 0, 0, 0);
    }
    f32x4 acc0 = acc0a + acc0b, acc1 = acc1a + acc1b;

    int rbase = mhalf * 16 + ((lane >> 4) << 2);
    int cix   = npair * 32 + (lane & 15);
    #pragma unroll
    for (int v = 0; v < 4; ++v) {
        gates[rbase + v][cix]      = acc0[v];
        gates[rbase + v][cix + 16] = acc1[v];
    }
    __syncthreads();

    int hu  = tid >> 5;
    int hid = gg * 8 + hu;
    float bi  = b_ih[hid]        + b_hh[hid];
    float bf_ = b_ih[512 + hid]  + b_hh[512 + hid];
    float bgt = b_ih[1024 + hid] + b_hh[1024 + hid];
    float bo  = b_ih[1536 + hid] + b_hh[1536 + hid];
    #pragma unroll
    for (int u = 0; u < 2; ++u) {
        int bl = ((tid & 31) << 1) + u;
        int b  = bg * 64 + bl;
        int br = base_rows[b];
        bool fp = (br + stepi) >= LSEQ;
        float gi = gates[hu][bl]      + bi;
        float gf = gates[8 + hu][bl]  + bf_;
        float gc = gates[16 + hu][bl] + bgt;
        float go = gates[24 + hu][bl] + bo;
        float cold = c_st[(size_t)b * HIDD + hid];
        float c2 = sigm(gf) * cold + sigm(gi) * tanhf(gc);
        float h2 = sigm(go) * tanhf(c2);
        unsigned short hb;
        if (fp) {
            hb = xh_in[(size_t)b * KDIM + EMBD + hid];
        } else {
            hb = f2bf(h2);
            c_st[(size_t)b * HIDD + hid] = c2;
        }
        hstage[bl][hu] = hb;
    }
    __syncthreads();
    if (tid < 64) {
        int b = bg * 64 + tid;
        short8x hv = *((const short8x*)&hstage[tid][0]);
        *((short8x*)(xh_out + (size_t)b * KDIM + EMBD + gg * 8)) = hv;
    }
    if (do_gather) {
        int b = wg;
        int br = base_rows[b];
        int row = br + stepi + 1; if (row > LSEQ - 1) row = LSEQ - 1;
        int tok = xs[(size_t)row * BATCH + b];
        float ev = embW[(size_t)tok * EMBD + tid] *
                   mask[((size_t)row * BATCH + b) * EMBD + tid];
        xh_out[(size_t)b * KDIM + tid] = f2bf(ev);
    }
}

__global__ __launch_bounds__(256) void boundary_kernel(
    unsigned short* xh,
    int* __restrict__ base_rows,
    const float* __restrict__ W_jump, const float* __restrict__ b_jump,
    const float* __restrict__ W_base, const float* __restrict__ b_base,
    const float* __restrict__ gumbel,
    float* __restrict__ lp_arr, float* __restrict__ base_arr,
    const int* __restrict__ xs, const float* __restrict__ embW,
    const float* __restrict__ mask,
    int n, int do_gather)
{
    __shared__ float zsh[42];
    __shared__ int rowsh;
    int b = blockIdx.x;
    int tid = threadIdx.x, lane = tid & 63, w = tid >> 6;

    const unsigned short* hp = xh + (size_t)b * KDIM + EMBD;
    union { short8x v; unsigned short u[8]; } hv;
    hv.v = *(const short8x*)(hp + lane * 8);
    float hf[8];
    #pragma unroll
    for (int j = 0; j < 8; ++j) hf[j] = bf2f(hv.u[j]);

    for (int r = w; r < 42; r += 4) {
        const float* wr = (r < NJ) ? (W_jump + (size_t)r * HIDD) : W_base;
        const float4* wp = (const float4*)(wr + lane * 8);
        float4 w0 = wp[0], w1 = wp[1];
        float acc = w0.x*hf[0] + w0.y*hf[1] + w0.z*hf[2] + w0.w*hf[3]
                  + w1.x*hf[4] + w1.y*hf[5] + w1.z*hf[6] + w1.w*hf[7];
        #pragma unroll
        for (int off = 32; off > 0; off >>= 1) acc += __shfl_down(acc, off, 64);
        if (lane == 0) zsh[r] = acc + ((r < NJ) ? b_jump[r] : b_base[0]);
    }
    __syncthreads();

    if (tid == 0) {
        const float* g = gumbel + ((size_t)n * BATCH + b) * NJ;
        float m = -1e30f, mg = -1e30f; int jm = 0;
        for (int r = 0; r < NJ; ++r) {
            float z = zsh[r];
            if (z > m) m = z;
            float zg = z + g[r];
            if (zg > mg) { mg = zg; jm = r; }
        }
        float s = 0.0f;
        for (int r = 0; r < NJ; ++r) s += expf(zsh[r] - m);
        float lse = m + logf(s);
        int br = base_rows[b];
        bool fp = (br + 20) >= LSEQ;
        lp_arr[n * BATCH + b]   = fp ? 0.0f : (zsh[jm] - lse);
        base_arr[n * BATCH + b] = zsh[41];
        int reff = br + 20; if (reff > LSEQ - 1) reff = LSEQ - 1;
        int nbr = (jm == 0) ? LSEQ : (reff + jm);
        base_rows[b] = nbr;
        rowsh = (nbr > LSEQ - 1) ? (LSEQ - 1) : nbr;
    }
    __syncthreads();

    if (do_gather) {
        int row = rowsh;
        int tok = xs[(size_t)row * BATCH + b];
        float ev = embW[(size_t)tok * EMBD + tid] *
                   mask[((size_t)row * BATCH + b) * EMBD + tid];
        xh[(size_t)b * KDIM + tid] = f2bf(ev);
    }
}

__global__ __launch_bounds__(256) void final_kernel(
    const unsigned short* __restrict__ xh,
    const float* __restrict__ W_out, const float* __restrict__ b_out,
    const int* __restrict__ tcls,
    const float* __restrict__ lp_arr, const float* __restrict__ base_arr,
    float* __restrict__ out)
{
    __shared__ float red[256];
    int b = threadIdx.x;
    const unsigned short* hp = xh + (size_t)b * KDIM + EMBD;
    float y[5];
    for (int c = 0; c < 5; ++c) {
        const float* wr = W_out + (size_t)c * HIDD;
        float acc = 0.0f;
        for (int k = 0; k < HIDD; k += 8) {
            union { short8x v; unsigned short u[8]; } hv;
            hv.v = *(const short8x*)(hp + k);
            #pragma unroll
            for (int j = 0; j < 8; ++j) acc += wr[k + j] * bf2f(hv.u[j]);
        }
        y[c] = acc + b_out[c];
    }
    float m = y[0]; int am = 0;
    for (int c = 1; c < 5; ++c) if (y[c] > m) { m = y[c]; am = c; }
    float s = 0.0f;
    for (int c = 0; c < 5; ++c) s += expf(y[c] - m);
    float lse = m + logf(s);
    int tb = tcls[b];
    float nll_p  = -(y[tb] - lse) * (1.0f / BATCH);
    float reward = (am == tb) ? 1.0f : -1.0f;
    float rp = 0.0f, mp = 0.0f;
    for (int nn = 0; nn < 5; ++nn) {
        float bs = base_arr[nn * BATCH + b];
        float lp = lp_arr[nn * BATCH + b];
        rp += -(reward - bs) * lp;
        float d = bs - reward;
        mp += d * d;
    }
    red[b] = nll_p + rp * (1.0f / (5.0f * BATCH)) + mp;
    __syncthreads();
    for (int off = 128; off > 0; off >>= 1) {
        if (b < off) red[b] += red[b + off];
        __syncthreads();
    }
    if (b == 0) out[0] = red[0];
}

// ---------------------------------------------------------------------------
extern "C" void kernel_launch(void* const* d_in, const int* in_sizes, int n_in,
                              void* d_out, int out_size, void* d_ws, size_t ws_size,
                              hipStream_t stream)
{
    (void)in_sizes; (void)n_in; (void)out_size; (void)ws_size;
    const int*   xs     = (const int*)d_in[0];
    const int*   tcls   = (const int*)d_in[2];
    const float* embW   = (const float*)d_in[3];
    const float* W_ih   = (const float*)d_in[4];
    const float* W_hh   = (const float*)d_in[5];
    const float* b_ih   = (const float*)d_in[6];
    const float* b_hh   = (const float*)d_in[7];
    const float* W_out  = (const float*)d_in[8];
    const float* b_out  = (const float*)d_in[9];
    const float* W_jump = (const float*)d_in[10];
    const float* b_jump = (const float*)d_in[11];
    const float* W_base = (const float*)d_in[12];
    const float* b_base = (const float*)d_in[13];
    const float* mask   = (const float*)d_in[14];
    const float* gumbel = (const float*)d_in[15];

    char* wsp = (char*)d_ws;
    unsigned short* pW  = (unsigned short*)(wsp);                 // 3,145,728 B
    unsigned short* xh  = (unsigned short*)(wsp + 3145728);       //   786,432 B
    float*    c_st      = (float*)(wsp + 3932160);                //   524,288 B (fallback)
    int*      base_rows = (int*)(wsp + 4456448);                  //     1,024 B
    float*    lp_arr    = (float*)(wsp + 4457472);                //     5,120 B
    float*    base_arr  = (float*)(wsp + 4462592);                //     5,120 B
    float*    loss_arr  = (float*)(wsp + 4467712);                //     1,024 B
    unsigned* flags     = (unsigned*)(wsp + 4468736);             //    32,768 B (256 x 128B)
    unsigned* go        = (unsigned*)(wsp + 4501504);             //       128 B
    float*    outp      = (float*)d_out;

    const size_t XH = (size_t)BATCH * KDIM;

    prologue_kernel<<<256, 256, 0, stream>>>(W_ih, W_hh, xs, embW, mask,
                                             pW, xh, c_st, base_rows, flags, go);

    void* args[] = {
        (void*)&pW, (void*)&xh, (void*)&base_rows,
        (void*)&b_ih, (void*)&b_hh, (void*)&xs, (void*)&embW, (void*)&mask,
        (void*)&W_jump, (void*)&b_jump, (void*)&W_base, (void*)&b_base,
        (void*)&gumbel, (void*)&lp_arr, (void*)&base_arr,
        (void*)&W_out, (void*)&b_out, (void*)&tcls,
        (void*)&loss_arr, (void*)&flags, (void*)&go, (void*)&outp
    };
    hipError_t err = hipLaunchCooperativeKernel((const void*)persistent_kernel,
                                                dim3(256), dim3(256), args, 0, stream);
    if (err != hipSuccess) {
        // Fallback: proven multi-kernel path (R2).
        int p = 0;
        for (int s = 0; s < 105; ++s) {
            int i = s % 21;
            step_kernel<<<256, 256, 0, stream>>>(pW, xh + (size_t)p * XH,
                                                 xh + (size_t)(p ^ 1) * XH,
                                                 c_st, base_rows, b_ih, b_hh,
                                                 xs, embW, mask, i, (i < 20) ? 1 : 0);
            p ^= 1;
            if (i == 20) {
                int n = s / 21;
                boundary_kernel<<<256, 256, 0, stream>>>(xh + (size_t)p * XH, base_rows,
                                                         W_jump, b_jump, W_base, b_base,
                                                         gumbel, lp_arr, base_arr,
                                                         xs, embW, mask,
                                                         n, (n < 4) ? 1 : 0);
            }
        }
        final_kernel<<<1, 256, 0, stream>>>(xh + (size_t)p * XH, W_out, b_out, tcls,
                                            lp_arr, base_arr, outp);
    }
}

// Round 7
// 1037.840 us; speedup vs baseline: 3.7320x; 1.5677x over previous
//
#include <hip/hip_runtime.h>

#define LSEQ 400
#define BATCH 256
#define EMBD 256
#define HIDD 512
#define KDIM 768   // EMB + HID
#define NJ 41      // K+1
#define RLX __ATOMIC_RELAXED
#define AGT __HIP_MEMORY_SCOPE_AGENT

typedef __attribute__((ext_vector_type(8))) short short8x;
typedef __attribute__((ext_vector_type(4))) float f32x4;
typedef unsigned long long u64;

union BQ { short8x v; unsigned short u[8]; u64 q[2]; };

__device__ __forceinline__ float bf2f(unsigned short u) {
    union { unsigned int i; float f; } v; v.i = ((unsigned int)u) << 16; return v.f;
}
__device__ __forceinline__ unsigned short f2bf(float f) {
    union { float f; unsigned int i; } v; v.f = f;
    unsigned int x = v.i;
    return (unsigned short)((x + 0x7fffu + ((x >> 16) & 1u)) >> 16);
}
__device__ __forceinline__ float sigm(float x) { return 1.0f / (1.0f + __expf(-x)); }

__device__ __forceinline__ u64 ald(const u64* p) {
    return __hip_atomic_load((u64*)p, RLX, AGT);
}
__device__ __forceinline__ void ast(u64* p, u64 v) {
    __hip_atomic_store(p, v, RLX, AGT);
}

// ---------------------------------------------------------------------------
// Prologue. New pW layout: [rg(32)][w(4)][kt(24)][lane(64)] x short8.
// Wave w = gate w; A row m = lane&15 -> W row = w*512 + rg*16 + (lane&15);
// k = kt*32 + (lane>>4)*8 + j (same proven bijection as R2-R6).
// ---------------------------------------------------------------------------
__global__ __launch_bounds__(256) void prologue_kernel(
    const float* __restrict__ W_ih, const float* __restrict__ W_hh,
    const int* __restrict__ xs, const float* __restrict__ embW,
    const float* __restrict__ mask,
    unsigned short* __restrict__ pW, unsigned short* __restrict__ xh0,
    int* __restrict__ base_rows, unsigned* __restrict__ flags)
{
    int wid = blockIdx.x, t = threadIdx.x;
    int rg = wid >> 3, sub = wid & 7;
    int lane = t & 63, subw = t >> 6;
    for (int q = 0; q < 3; ++q) {
        int G = sub * 12 + subw * 3 + q;     // 0..95 = w(4) x kt(24)
        int w = G / 24, kt = G % 24;
        int grow = w * 512 + rg * 16 + (lane & 15);
        int k0 = kt * 32 + ((lane >> 4) << 3);
        BQ pk;
        #pragma unroll
        for (int j = 0; j < 8; ++j) {
            int k = k0 + j;
            float wv = (k < EMBD) ? W_ih[(size_t)grow * EMBD + k]
                                  : W_hh[(size_t)grow * HIDD + (k - EMBD)];
            pk.u[j] = f2bf(wv);
        }
        ((short8x*)pW)[((size_t)(rg * 4 + w) * 24 + kt) * 64 + lane] = pk.v;
    }
    // per-batch state init (b = wid): x for step 0 (row 0), h=0, base=0
    int b = wid;
    int tok = xs[b];   // row 0
    float ev = embW[(size_t)tok * EMBD + t] * mask[(size_t)b * EMBD + t];
    xh0[(size_t)b * KDIM + t] = f2bf(ev);
    for (int e = t; e < HIDD; e += 256) xh0[(size_t)b * KDIM + EMBD + e] = 0;
    if (t == 0) base_rows[b] = 0;
    if (t < 32) flags[wid * 32 + t] = 0u;
}

// ---------------------------------------------------------------------------
// Persistent kernel. 256 WGs = 8 col-groups (cg) x 32 row-groups (rg).
// WG(cg,rg): 64 gate rows (16 units x 4 gates) x 32 cols; owns col
// colg = cg*32+rg for gather/boundary/loss. B staged sc1->LDS once per WG
// (4x less L3 traffic than R6); per-col-group 32-WG flag barrier.
// All data flow is col-group-local; no cross-group coupling until reduce.
// ---------------------------------------------------------------------------
__global__ __launch_bounds__(256, 1) void persistent_kernel(
    const unsigned short* __restrict__ pW,
    unsigned short* __restrict__ xh,           // 2 double-buffered [256][768]
    int* __restrict__ base_rows,
    const float* __restrict__ b_ih, const float* __restrict__ b_hh,
    const int* __restrict__ xs, const float* __restrict__ embW,
    const float* __restrict__ mask,
    const float* __restrict__ W_jump, const float* __restrict__ b_jump,
    const float* __restrict__ W_base, const float* __restrict__ b_base,
    const float* __restrict__ gumbel,
    float* __restrict__ lp_arr, float* __restrict__ base_arr,
    const float* __restrict__ W_out, const float* __restrict__ b_out,
    const int* __restrict__ tcls,
    float* __restrict__ loss_arr, unsigned* __restrict__ flags)
{
    __shared__ u64 Bsh[32 * 193];                 // [32 cols][772 shorts] padded
    __shared__ float gates[4][16][33];            // [gate][unit][col+pad]
    __shared__ __align__(8) unsigned short hstage[32][16];   // [col][unit]
    __shared__ __align__(8) unsigned short xstage[256];
    __shared__ float zsh[42];
    __shared__ int rowsh, nbrsh;

    const int wg = blockIdx.x;
    const int cg = wg >> 5, rg = wg & 31;
    const int colg = cg * 32 + rg;                // owned column
    const int tid = threadIdx.x, lane = tid & 63, w = tid >> 6;

    // --- A fragments: 24 x short8x per wave (gate w, units rg*16..+16) ---
    short8x A[24];
    {
        const short8x* Ab = ((const short8x*)pW) + ((size_t)(rg * 4 + w) * 24) * 64 + lane;
        #pragma unroll
        for (int kt = 0; kt < 24; ++kt) A[kt] = Ab[kt * 64];
    }

    // --- elementwise mapping: unit u = tid>>4, two local cols ---
    const int u = tid >> 4;
    const int lc0 = (tid & 15) << 1;
    const int hid = rg * 16 + u;
    const float bi  = b_ih[hid]        + b_hh[hid];
    const float bf_ = b_ih[512 + hid]  + b_hh[512 + hid];
    const float bgt = b_ih[1024 + hid] + b_hh[1024 + hid];
    const float bo  = b_ih[1536 + hid] + b_hh[1536 + hid];

    float c0 = 0.f, c1 = 0.f, h0 = 0.f, h1 = 0.f;   // state for my 2 cols
    int brc0 = 0, brc1 = 0;                          // base rows for my 2 cols
    int rowg = 0;                                    // base row of owned colg

    unsigned bar = 0;
    const size_t XH = (size_t)BATCH * KDIM;
    int p = 0;

    for (int n = 0; n < 5; ++n) {
        for (int i = 0; i <= 20; ++i) {
            const unsigned short* xin  = xh + (size_t)p * XH;
            unsigned short*       xout = xh + (size_t)(p ^ 1) * XH;

            // (1) issue gather loads early (owned col; read-only data, plain)
            float ge = 0.f, gm = 0.f;
            if (i < 20) {
                int row = rowg + i + 1; if (row > LSEQ - 1) row = LSEQ - 1;
                int tok = xs[(size_t)row * BATCH + colg];
                ge = embW[(size_t)tok * EMBD + tid];
                gm = mask[((size_t)row * BATCH + colg) * EMBD + tid];
            }

            // (2) stage B block (32 cols x 768 k) sc1 -> LDS, once per WG
            {
                const u64* gsrc = (const u64*)(xin + (size_t)cg * 32 * KDIM);
                #pragma unroll 4
                for (int j = 0; j < 24; ++j) {
                    unsigned g = (unsigned)(j * 256 + tid);   // 0..6143
                    unsigned col = g / 192u, qw = g % 192u;
                    Bsh[col * 193u + qw] = ald(gsrc + g);
                }
            }
            __syncthreads();

            // (3) MFMA: wave w = gate w; 2 n-tiles of 16 cols; dual kt chains
            f32x4 aA0 = {0,0,0,0}, aB0 = {0,0,0,0};
            f32x4 aA1 = {0,0,0,0}, aB1 = {0,0,0,0};
            {
                const u64* bc0 = &Bsh[(size_t)(lane & 15) * 193 + ((lane >> 4) << 1)];
                const u64* bc1 = bc0 + 16 * 193;
                #pragma unroll
                for (int kt = 0; kt < 24; kt += 2) {
                    BQ q00, q10, q01, q11;
                    q00.q[0] = bc0[kt * 8];     q00.q[1] = bc0[kt * 8 + 1];
                    q10.q[0] = bc1[kt * 8];     q10.q[1] = bc1[kt * 8 + 1];
                    q01.q[0] = bc0[kt * 8 + 8]; q01.q[1] = bc0[kt * 8 + 9];
                    q11.q[0] = bc1[kt * 8 + 8]; q11.q[1] = bc1[kt * 8 + 9];
                    aA0 = __builtin_amdgcn_mfma_f32_16x16x32_bf16(A[kt],     q00.v, aA0, 0, 0, 0);
                    aA1 = __builtin_amdgcn_mfma_f32_16x16x32_bf16(A[kt],     q10.v, aA1, 0, 0, 0);
                    aB0 = __builtin_amdgcn_mfma_f32_16x16x32_bf16(A[kt + 1], q01.v, aB0, 0, 0, 0);
                    aB1 = __builtin_amdgcn_mfma_f32_16x16x32_bf16(A[kt + 1], q11.v, aB1, 0, 0, 0);
                }
            }
            f32x4 acc0 = aA0 + aB0, acc1 = aA1 + aB1;
            {
                int ur = (lane >> 4) << 2;
                int cl = lane & 15;
                #pragma unroll
                for (int v = 0; v < 4; ++v) {   // D: unit=(lane>>4)*4+v, col=lane&15
                    gates[w][ur + v][cl]      = acc0[v];
                    gates[w][ur + v][cl + 16] = acc1[v];
                }
            }
            __syncthreads();

            // (4) elementwise LSTM on resident state (2 cols)
            {
                bool fp = (brc0 + i) >= LSEQ;
                float gi = gates[0][u][lc0] + bi;
                float gf = gates[1][u][lc0] + bf_;
                float gc = gates[2][u][lc0] + bgt;
                float go = gates[3][u][lc0] + bo;
                float c2 = sigm(gf) * c0 + sigm(gi) * tanhf(gc);
                float h2 = sigm(go) * tanhf(c2);
                if (!fp) { c0 = c2; h0 = h2; }
                hstage[lc0][u] = f2bf(h0);
            }
            {
                bool fp = (brc1 + i) >= LSEQ;
                float gi = gates[0][u][lc0 + 1] + bi;
                float gf = gates[1][u][lc0 + 1] + bf_;
                float gc = gates[2][u][lc0 + 1] + bgt;
                float go = gates[3][u][lc0 + 1] + bo;
                float c2 = sigm(gf) * c1 + sigm(gi) * tanhf(gc);
                float h2 = sigm(go) * tanhf(c2);
                if (!fp) { c1 = c2; h1 = h2; }
                hstage[lc0 + 1][u] = f2bf(h1);
            }
            if (i < 20) xstage[tid] = f2bf(ge * gm);
            __syncthreads();

            // (5) sc1 stores: h slice (16 units x 32 cols) + owned col's x
            if (tid < 128) {
                int col = tid >> 2, qd = tid & 3;
                u64 hv = ((const u64*)&hstage[col][0])[qd];
                ast((u64*)(xout + (size_t)(cg * 32 + col) * KDIM + EMBD + rg * 16) + qd, hv);
            }
            if (i < 20 && tid < 64) {
                ast((u64*)(xout + (size_t)colg * KDIM) + tid, ((const u64*)xstage)[tid]);
            }
            p ^= 1;

            // (6) per-col-group barrier (32 flags, contention-free)
            ++bar;
            asm volatile("s_waitcnt vmcnt(0) lgkmcnt(0)" ::: "memory");
            __syncthreads();
            if (tid == 0) __hip_atomic_store(&flags[wg * 32], bar, RLX, AGT);
            if (tid < 32) {
                while (__hip_atomic_load(&flags[(cg * 32 + tid) * 32], RLX, AGT) < bar)
                    __builtin_amdgcn_s_sleep(1);
            }
            __syncthreads();

            if (i == 20) {
                // ---------------- boundary (owned col) ----------------------
                unsigned short* xcur = xh + (size_t)p * XH;
                BQ hv;
                const u64* hq = (const u64*)(xcur + (size_t)colg * KDIM + EMBD) + lane * 2;
                hv.q[0] = ald(hq);
                hv.q[1] = ald(hq + 1);
                float hf[8];
                #pragma unroll
                for (int q = 0; q < 8; ++q) hf[q] = bf2f(hv.u[q]);

                for (int r = w; r < 42; r += 4) {
                    const float* wr = (r < NJ) ? (W_jump + (size_t)r * HIDD) : W_base;
                    const float4* wp = (const float4*)(wr + lane * 8);
                    float4 w0 = wp[0], w1 = wp[1];
                    float acc = w0.x*hf[0] + w0.y*hf[1] + w0.z*hf[2] + w0.w*hf[3]
                              + w1.x*hf[4] + w1.y*hf[5] + w1.z*hf[6] + w1.w*hf[7];
                    #pragma unroll
                    for (int off = 32; off > 0; off >>= 1) acc += __shfl_down(acc, off, 64);
                    if (lane == 0) zsh[r] = acc + ((r < NJ) ? b_jump[r] : b_base[0]);
                }
                __syncthreads();

                if (tid == 0) {
                    const float* g = gumbel + ((size_t)n * BATCH + colg) * NJ;
                    float m = -1e30f, mg = -1e30f; int jm = 0;
                    for (int r = 0; r < NJ; ++r) {
                        float z = zsh[r];
                        if (z > m) m = z;
                        float zg = z + g[r];
                        if (zg > mg) { mg = zg; jm = r; }   // strict > tiebreak
                    }
                    float s = 0.0f;
                    for (int r = 0; r < NJ; ++r) s += expf(zsh[r] - m);
                    float lse = m + logf(s);
                    int br = rowg;
                    bool fp = (br + 20) >= LSEQ;
                    lp_arr[n * BATCH + colg]   = fp ? 0.0f : (zsh[jm] - lse);  // plain: own-WG consumer
                    base_arr[n * BATCH + colg] = zsh[41];
                    int reff = br + 20; if (reff > LSEQ - 1) reff = LSEQ - 1;
                    int nbr = (jm == 0) ? LSEQ : (reff + jm);
                    __hip_atomic_store(&base_rows[colg], nbr, RLX, AGT);
                    nbrsh = nbr;
                    rowsh = (nbr > LSEQ - 1) ? (LSEQ - 1) : nbr;
                }
                __syncthreads();

                if (n < 4) {                    // gather first x of next outer
                    int row = rowsh;
                    int tok = xs[(size_t)row * BATCH + colg];
                    float ev = embW[(size_t)tok * EMBD + tid] *
                               mask[((size_t)row * BATCH + colg) * EMBD + tid];
                    xstage[tid] = f2bf(ev);
                }
                rowg = nbrsh;
                __syncthreads();
                if (n < 4 && tid < 64) {
                    ast((u64*)(xcur + (size_t)colg * KDIM) + tid, ((const u64*)xstage)[tid]);
                }

                // group barrier again, then refresh per-col base rows
                ++bar;
                asm volatile("s_waitcnt vmcnt(0) lgkmcnt(0)" ::: "memory");
                __syncthreads();
                if (tid == 0) __hip_atomic_store(&flags[wg * 32], bar, RLX, AGT);
                if (tid < 32) {
                    while (__hip_atomic_load(&flags[(cg * 32 + tid) * 32], RLX, AGT) < bar)
                        __builtin_amdgcn_s_sleep(1);
                }
                __syncthreads();
                brc0 = __hip_atomic_load(&base_rows[cg * 32 + lc0],     RLX, AGT);
                brc1 = __hip_atomic_load(&base_rows[cg * 32 + lc0 + 1], RLX, AGT);
            }
        }
    }

    // ---------------- final: per-col loss (owned col) -----------------------
    {
        const unsigned short* xcur = xh + (size_t)p * XH;
        BQ hv;
        const u64* hq = (const u64*)(xcur + (size_t)colg * KDIM + EMBD) + lane * 2;
        hv.q[0] = ald(hq);
        hv.q[1] = ald(hq + 1);
        float hf[8];
        #pragma unroll
        for (int q = 0; q < 8; ++q) hf[q] = bf2f(hv.u[q]);

        for (int r = w; r < 5; r += 4) {
            const float4* wp = (const float4*)(W_out + (size_t)r * HIDD + lane * 8);
            float4 w0 = wp[0], w1 = wp[1];
            float acc = w0.x*hf[0] + w0.y*hf[1] + w0.z*hf[2] + w0.w*hf[3]
                      + w1.x*hf[4] + w1.y*hf[5] + w1.z*hf[6] + w1.w*hf[7];
            #pragma unroll
            for (int off = 32; off > 0; off >>= 1) acc += __shfl_down(acc, off, 64);
            if (lane == 0) zsh[r] = acc + b_out[r];
        }
        __syncthreads();

        if (tid == 0) {
            float y[5];
            #pragma unroll
            for (int c = 0; c < 5; ++c) y[c] = zsh[c];
            float m = y[0]; int am = 0;
            for (int c = 1; c < 5; ++c) if (y[c] > m) { m = y[c]; am = c; }
            float s = 0.0f;
            for (int c = 0; c < 5; ++c) s += expf(y[c] - m);
            float lse = m + logf(s);
            int tb = tcls[colg];
            float nll_p  = -(y[tb] - lse) * (1.0f / BATCH);
            float reward = (am == tb) ? 1.0f : -1.0f;
            float rp = 0.0f, mp = 0.0f;
            for (int nn = 0; nn < 5; ++nn) {
                float bs = base_arr[nn * BATCH + colg];
                float lp = lp_arr[nn * BATCH + colg];
                rp += -(reward - bs) * lp;
                float d = bs - reward;
                mp += d * d;
            }
            loss_arr[colg] = nll_p + rp * (1.0f / (5.0f * BATCH)) + mp;
        }
    }
}

// ---------------------------------------------------------------------------
// Final reduce: 1 WG, tree-sum of 256 per-col losses (cross-kernel visibility
// via kernel-boundary release).
// ---------------------------------------------------------------------------
__global__ __launch_bounds__(256) void reduce_kernel(
    const float* __restrict__ loss_arr, float* __restrict__ out)
{
    __shared__ float red[256];
    int t = threadIdx.x;
    red[t] = loss_arr[t];
    __syncthreads();
    for (int off = 128; off > 0; off >>= 1) {
        if (t < off) red[t] += red[t + off];
        __syncthreads();
    }
    if (t == 0) out[0] = red[0];
}

// ---------------------------------------------------------------------------
extern "C" void kernel_launch(void* const* d_in, const int* in_sizes, int n_in,
                              void* d_out, int out_size, void* d_ws, size_t ws_size,
                              hipStream_t stream)
{
    (void)in_sizes; (void)n_in; (void)out_size; (void)ws_size;
    const int*   xs     = (const int*)d_in[0];
    const int*   tcls   = (const int*)d_in[2];
    const float* embW   = (const float*)d_in[3];
    const float* W_ih   = (const float*)d_in[4];
    const float* W_hh   = (const float*)d_in[5];
    const float* b_ih   = (const float*)d_in[6];
    const float* b_hh   = (const float*)d_in[7];
    const float* W_out  = (const float*)d_in[8];
    const float* b_out  = (const float*)d_in[9];
    const float* W_jump = (const float*)d_in[10];
    const float* b_jump = (const float*)d_in[11];
    const float* W_base = (const float*)d_in[12];
    const float* b_base = (const float*)d_in[13];
    const float* mask   = (const float*)d_in[14];
    const float* gumbel = (const float*)d_in[15];

    char* wsp = (char*)d_ws;
    unsigned short* pW  = (unsigned short*)(wsp);                 // 3,145,728 B
    unsigned short* xh  = (unsigned short*)(wsp + 3145728);       //   786,432 B
    int*      base_rows = (int*)(wsp + 3932160);                  //     1,024 B
    float*    lp_arr    = (float*)(wsp + 3933184);                //     5,120 B
    float*    base_arr  = (float*)(wsp + 3938304);                //     5,120 B
    float*    loss_arr  = (float*)(wsp + 3943424);                //     1,024 B
    unsigned* flags     = (unsigned*)(wsp + 3944448);             //    32,768 B
    float*    outp      = (float*)d_out;

    prologue_kernel<<<256, 256, 0, stream>>>(W_ih, W_hh, xs, embW, mask,
                                             pW, xh, base_rows, flags);

    void* args[] = {
        (void*)&pW, (void*)&xh, (void*)&base_rows,
        (void*)&b_ih, (void*)&b_hh, (void*)&xs, (void*)&embW, (void*)&mask,
        (void*)&W_jump, (void*)&b_jump, (void*)&W_base, (void*)&b_base,
        (void*)&gumbel, (void*)&lp_arr, (void*)&base_arr,
        (void*)&W_out, (void*)&b_out, (void*)&tcls,
        (void*)&loss_arr, (void*)&flags
    };
    hipError_t err = hipLaunchCooperativeKernel((const void*)persistent_kernel,
                                                dim3(256), dim3(256), args, 0, stream);
    if (err != hipSuccess) {
        // Same kernel, plain launch: 256 WGs x 1/CU are co-resident in practice.
        persistent_kernel<<<256, 256, 0, stream>>>(
            pW, xh, base_rows, b_ih, b_hh, xs, embW, mask,
            W_jump, b_jump, W_base, b_base, gumbel, lp_arr, base_arr,
            W_out, b_out, tcls, loss_arr, flags);
    }
    reduce_kernel<<<1, 256, 0, stream>>>(loss_arr, outp);
}